// Round 21
// baseline (499.104 us; speedup 1.0000x reference)
//
#include <hip/hip_runtime.h>
#include <hip/hip_bf16.h>
#include <float.h>
#include <math.h>

typedef __hip_bfloat16 bf16;
typedef float v2f __attribute__((ext_vector_type(2)));

#define NEGBIG (-1e30f)

__device__ __forceinline__ float ldv(const float* p, int i) { return p[i]; }

__device__ __forceinline__ float wave_sum(float v) {
#pragma unroll
  for (int off = 32; off; off >>= 1) v += __shfl_xor(v, off, 64);
  return v;
}
__device__ __forceinline__ float wave_max(float v) {
#pragma unroll
  for (int off = 32; off; off >>= 1) v = fmaxf(v, __shfl_xor(v, off, 64));
  return v;
}

__device__ __forceinline__ float rdlane(float v, int l) {
  return __uint_as_float(__builtin_amdgcn_readlane(__float_as_uint(v), l));
}

// PV over 16 tokens: p = lanes L0..L0+15 of e (readlane -> SALU broadcast),
// V rows at vp + t*64 floats (imm offsets). 4 chains.
template <int L0>
__device__ __forceinline__ void pv16(const float* __restrict__ vp, float e,
                                     float& a0, float& a1, float& a2, float& a3) {
#pragma unroll
  for (int t = 0; t < 16; t += 4) {
    float p0 = rdlane(e, L0 + t + 0);
    float p1 = rdlane(e, L0 + t + 1);
    float p2 = rdlane(e, L0 + t + 2);
    float p3 = rdlane(e, L0 + t + 3);
    a0 += p0 * vp[(t + 0) * 64];
    a1 += p1 * vp[(t + 1) * 64];
    a2 += p2 * vp[(t + 2) * 64];
    a3 += p3 * vp[(t + 3) * 64];
  }
}

// QK dot against one 32-token K block slice, packed (v_pk_fma_f32).
__device__ __forceinline__ float qk_dot(const float4* __restrict__ qr,
                                        const float4* __restrict__ kp) {
  v2f d01 = {0.f, 0.f}, d23 = {0.f, 0.f};
#pragma unroll 1
  for (int i = 0; i < 16; i += 2) {
    float4 q0 = qr[i],     k0 = kp[i * 32];
    float4 q1 = qr[i + 1], k1 = kp[i * 32 + 32];
    d01 += (v2f){q0.x, q0.y} * (v2f){k0.x, k0.y};
    d23 += (v2f){q0.z, q0.w} * (v2f){k0.z, k0.w};
    d01 += (v2f){q1.x, q1.y} * (v2f){k1.x, k1.y};
    d23 += (v2f){q1.z, q1.w} * (v2f){k1.z, k1.w};
  }
  v2f d = d01 + d23;
  return d.x + d.y;
}

// ---------------- pipelined f32 GEMM core: 64x64 tile, 8x4 microtile ---------
// 128 threads (16x8 microtile grid). LDS traffic 1.5 B/MAC (was 2.0 with 4x4)
// — r13-r19 chain measured 180us == LDS-roofline prediction at 2 B/MAC, so
// LDS BW is the GEMM bound. Per-output FMA order unchanged -> bitwise equal.
__device__ __forceinline__ void gemm_core(
    const float* __restrict__ A, const float* __restrict__ B, float* __restrict__ C,
    int K, int lda, int ldb, int ldc, int row0, int col0)
{
  __shared__ __align__(16) float As[2][16][68];
  __shared__ __align__(16) float Bs[2][16][68];
  const int tid = threadIdx.x;            // 128 threads
  const int tx = tid & 15, ty = tid >> 4; // 16 cols x 8 rows of microtiles
  const int ar = tid >> 1;                // A row 0..63
  const int ak = (tid & 1) * 8;           // A k-offset {0,8}
  const int bk = tid >> 3;                // B k-row 0..15
  const int bc = (tid & 7) * 8;           // B col offset {0,8,...,56}

  const int nk = K >> 4;
  float4 a40 = *reinterpret_cast<const float4*>(&A[(row0 + ar) * lda + ak]);
  float4 a41 = *reinterpret_cast<const float4*>(&A[(row0 + ar) * lda + ak + 4]);
  float4 b40 = *reinterpret_cast<const float4*>(&B[bk * ldb + col0 + bc]);
  float4 b41 = *reinterpret_cast<const float4*>(&B[bk * ldb + col0 + bc + 4]);
  {
    As[0][ak + 0][ar] = a40.x; As[0][ak + 1][ar] = a40.y;
    As[0][ak + 2][ar] = a40.z; As[0][ak + 3][ar] = a40.w;
    As[0][ak + 4][ar] = a41.x; As[0][ak + 5][ar] = a41.y;
    As[0][ak + 6][ar] = a41.z; As[0][ak + 7][ar] = a41.w;
    *reinterpret_cast<float4*>(&Bs[0][bk][bc]) = b40;
    *reinterpret_cast<float4*>(&Bs[0][bk][bc + 4]) = b41;
  }

  v2f acc01[8] = {};
  v2f acc23[8] = {};
  for (int t = 0; t < nk; ++t) {
    const int cur = t & 1;
    if (t + 1 < nk) {
      int k0 = (t + 1) * 16;
      a40 = *reinterpret_cast<const float4*>(&A[(row0 + ar) * lda + k0 + ak]);
      a41 = *reinterpret_cast<const float4*>(&A[(row0 + ar) * lda + k0 + ak + 4]);
      b40 = *reinterpret_cast<const float4*>(&B[(k0 + bk) * ldb + col0 + bc]);
      b41 = *reinterpret_cast<const float4*>(&B[(k0 + bk) * ldb + col0 + bc + 4]);
    }
    __syncthreads();
#pragma unroll
    for (int kk = 0; kk < 16; ++kk) {
      float4 av0 = *reinterpret_cast<const float4*>(&As[cur][kk][ty * 8]);
      float4 av1 = *reinterpret_cast<const float4*>(&As[cur][kk][ty * 8 + 4]);
      float4 bv  = *reinterpret_cast<const float4*>(&Bs[cur][kk][tx * 4]);
      v2f b01; b01.x = bv.x; b01.y = bv.y;
      v2f b23; b23.x = bv.z; b23.y = bv.w;
      float a[8] = {av0.x, av0.y, av0.z, av0.w, av1.x, av1.y, av1.z, av1.w};
#pragma unroll
      for (int i = 0; i < 8; ++i) {
        v2f as; as.x = a[i]; as.y = a[i];
        acc01[i] += as * b01;
        acc23[i] += as * b23;
      }
    }
    if (t + 1 < nk) {
      const int nxt = cur ^ 1;
      As[nxt][ak + 0][ar] = a40.x; As[nxt][ak + 1][ar] = a40.y;
      As[nxt][ak + 2][ar] = a40.z; As[nxt][ak + 3][ar] = a40.w;
      As[nxt][ak + 4][ar] = a41.x; As[nxt][ak + 5][ar] = a41.y;
      As[nxt][ak + 6][ar] = a41.z; As[nxt][ak + 7][ar] = a41.w;
      *reinterpret_cast<float4*>(&Bs[nxt][bk][bc]) = b40;
      *reinterpret_cast<float4*>(&Bs[nxt][bk][bc + 4]) = b41;
    }
  }
#pragma unroll
  for (int i = 0; i < 8; ++i) {
    float4 o = make_float4(acc01[i].x, acc01[i].y, acc23[i].x, acc23[i].y);
    *reinterpret_cast<float4*>(&C[(row0 + ty * 8 + i) * ldc + col0 + tx * 4]) = o;
  }
}

__global__ __launch_bounds__(128) void gemm_tile(
    const float* __restrict__ A, const float* __restrict__ B, float* __restrict__ C,
    int M, int N, int K, int lda, int ldb, int ldc)
{
  gemm_core(A, B, C, K, lda, ldb, ldc, blockIdx.y * 64, blockIdx.x * 64);
}

// Fused h-projections: hc (x<4), kb (x==4), vb (x==5). One dispatch, 192 blocks.
__global__ __launch_bounds__(128) void gemm_qckv(
    const float* __restrict__ h, const float* __restrict__ w_qc,
    const float* __restrict__ w_k, const float* __restrict__ w_v,
    float* __restrict__ hc, float* __restrict__ kb, float* __restrict__ vb)
{
  const int x = blockIdx.x;
  if (x < 4) {
    gemm_core(h, w_qc, hc, 1024, 1024, 256, 256, blockIdx.y * 64, x * 64);
  } else if (x == 4) {
    gemm_core(h, w_k, kb, 1024, 1024, 64, 64, blockIdx.y * 64, 0);
  } else {
    gemm_core(h, w_v, vb, 1024, 1024, 64, 64, blockIdx.y * 64, 0);
  }
}

// Fused pair of GEMMs over x-split grid: blockIdx.x < nx -> (A0,B0,C0).
__global__ __launch_bounds__(128) void gemm_dual(
    const float* __restrict__ A0, const float* __restrict__ A1,
    const float* __restrict__ B0, const float* __restrict__ B1,
    float* __restrict__ C0, float* __restrict__ C1,
    int K, int lda, int ldb, int ldc, int nx)
{
  const bool second = (int)blockIdx.x >= nx;
  const float* A = second ? A1 : A0;
  const float* B = second ? B1 : B0;
  float* C = second ? C1 : C0;
  const int bx = second ? (blockIdx.x - nx) : blockIdx.x;
  gemm_core(A, B, C, K, lda, ldb, ldc, blockIdx.y * 64, bx * 64);
}

// ---------------- RoPE cos/sin table (double trig once, f32 store) ----------
__global__ __launch_bounds__(256) void rope_table_kernel(float* __restrict__ ct,
                                                         float* __restrict__ st) {
  int tid = blockIdx.x * 256 + threadIdx.x;
  if (tid >= 2048 * 16) return;
  int pos = tid >> 4, i = tid & 15;
  double ang = (double)pos * pow(10000.0, -(double)i / 16.0);
  ct[tid] = (float)cos(ang);
  st[tid] = (float)sin(ang);
}

// ---------------- RoPE (first 32 dims) + RMSNorm (fused q+k) ----------------
__device__ __forceinline__ void rope_body(
    float* __restrict__ x, const float* __restrict__ g, int rows, int posShift,
    float* __restrict__ kS, const float* __restrict__ ct, const float* __restrict__ st,
    int bx)
{
  const int lane = threadIdx.x & 63;
  const int wid = threadIdx.x >> 6;
  const int r = bx * 4 + wid;
  if (r >= rows) return;
  const int pos = r >> posShift;
  float val = x[r * 64 + lane];
  float p = __shfl_xor(val, 16, 64);
  float out = val;
  if (lane < 32) {
    int i = lane & 15;
    float cc = ct[pos * 16 + i], ss = st[pos * 16 + i];
    out = (lane < 16) ? (val * cc - p * ss) : (p * ss + val * cc);
  }
  float ms = wave_sum(out * out) * (1.0f / 64.0f);
  float rn = rsqrtf(ms + 1e-6f);
  float res = out * rn * ldv(g, lane);
  x[r * 64 + lane] = res;
  if (kS) {
    int f4 = (r >> 5) * 512 + (lane >> 2) * 32 + (r & 31);
    kS[f4 * 4 + (lane & 3)] = res;
  }
}

__global__ __launch_bounds__(256) void rope_rms_fused(
    float* __restrict__ qx, float* __restrict__ kx,
    const float* __restrict__ gq, const float* __restrict__ gk,
    float* __restrict__ kS, const float* __restrict__ ct, const float* __restrict__ st)
{
  const int bx = blockIdx.x;
  if (bx < 4096) rope_body(qx, gq, 16384, 3, nullptr, ct, st, bx);
  else           rope_body(kx, gk, 2048, 0, kS, ct, st, bx - 4096);
}

// ---------------- block-mean compression: kcT4 (d4-major) + vc --------------
__global__ void compress_kernel(const float* __restrict__ k, const float* __restrict__ v,
                                float* __restrict__ kcT4, float* __restrict__ vc)
{
  const int n = blockIdx.x;
  const int d = threadIdx.x;
  float sk = 0.f, sv = 0.f;
  for (int j = 0; j < 32; ++j) {
    sk += k[(n * 32 + j) * 64 + d];
    sv += v[(n * 32 + j) * 64 + d];
  }
  kcT4[(d >> 2) * 256 + n * 4 + (d & 3)] = sk * (1.0f / 32.0f);
  vc[n * 64 + d] = sv * (1.0f / 32.0f);
}

// ---------------- attention: one wave per (qpos, head) — r19 form ------------
__global__ __launch_bounds__(256) void attn_kernel(
    const float* __restrict__ q, const float* __restrict__ kS, const float* __restrict__ vbuf,
    const float* __restrict__ kcT4, const float* __restrict__ vc,
    const float* __restrict__ w_gate, const float* __restrict__ b_gate,
    const float* __restrict__ sink, float* __restrict__ mixed)
{
  __shared__ __align__(16) float shq[4][64];
  __shared__ int shsel[4][16];
  const int lane = threadIdx.x & 63;
  const int wid = threadIdx.x >> 6;
  const int bid = 4095 - blockIdx.x;    // LJF: heaviest (large qpos) first
  const int r = bid * 4 + wid;          // r = qpos*8 + h
  const int qpos = r >> 3, h = r & 7;
  const float scale = 0.125f;

  float qv = q[r * 64 + lane];
  shq[wid][lane] = qv;

  // ---- gate ----
  float z0 = qv * ldv(w_gate, lane * 3 + 0);
  float z1 = qv * ldv(w_gate, lane * 3 + 1);
  float z2 = qv * ldv(w_gate, lane * 3 + 2);
  z0 = wave_sum(z0) + ldv(b_gate, 0);
  z1 = wave_sum(z1) + ldv(b_gate, 1);
  z2 = wave_sum(z2) + ldv(b_gate, 2);
  float ga0 = 1.f / (1.f + expf(-z0));
  float ga1 = 1.f / (1.f + expf(-z1));
  float ga2 = 1.f / (1.f + expf(-z2));
  float gs = fmaxf(ga0 + ga1 + ga2, 1e-6f);
  float ginv = 1.f / gs;
  ga0 *= ginv; ga1 *= ginv; ga2 *= ginv;

  const float4* qr = reinterpret_cast<const float4*>(&shq[wid][0]);
  const float4* ks4 = reinterpret_cast<const float4*>(kS);
  const float4* kct = reinterpret_cast<const float4*>(kcT4);  // [16][64]
  const float snk = ldv(sink, h);
  const int nv = (qpos + 1) >> 5;

  // ---- compressed scores (lane = block index) — scalar chains (top-k bitwise) ----
  float sc;
  {
    float d0 = 0.f, d1 = 0.f;
#pragma unroll 1
    for (int i = 0; i < 16; i += 2) {
      float4 q0 = qr[i],     k0 = kct[i * 64 + lane];
      float4 q1 = qr[i + 1], k1 = kct[(i + 1) * 64 + lane];
      d0 += q0.x * k0.x + q0.z * k0.z;
      d1 += q0.y * k0.y + q0.w * k0.w;
      d0 += q1.x * k1.x + q1.z * k1.z;
      d1 += q1.y * k1.y + q1.w * k1.w;
    }
    sc = (d0 + d1) * scale;
  }

  float comp_out = 0.f;
  if (nv > 0) {
    float scomp = (lane < nv) ? sc : NEGBIG;
    float m = fmaxf(wave_max(scomp), snk);
    float e = (lane < nv) ? expf(sc - m) : 0.f;
    float S = wave_sum(e) + expf(snk - m);
    float pn = e / S;   // zero for lane >= nv
    const float* vcp = vc + lane;
    float c0 = 0.f, c1 = 0.f, c2 = 0.f, c3 = 0.f;
    pv16<0>(vcp, pn, c0, c1, c2, c3);
    pv16<16>(vcp + 1024, pn, c0, c1, c2, c3);
    pv16<32>(vcp + 2048, pn, c0, c1, c2, c3);
    pv16<48>(vcp + 3072, pn, c0, c1, c2, c3);
    comp_out = (c0 + c1) + (c2 + c3);
  }

  // ---- top-16 block selection (jax.lax.top_k tie semantics) ----
  {
    float selv = (lane < nv) ? sc : -FLT_MAX;
#pragma unroll
    for (int it = 0; it < 16; ++it) {
      float bv = selv; int bi = lane;
#pragma unroll
      for (int off = 32; off; off >>= 1) {
        float ov = __shfl_xor(bv, off, 64);
        int oi = __shfl_xor(bi, off, 64);
        if (ov > bv || (ov == bv && oi < bi)) { bv = ov; bi = oi; }
      }
      if (lane == 0) shsel[wid][it] = bi;
      if (lane == bi) selv = -INFINITY;
    }
  }

  // ---- selected branch: 8 chunks x 2 blocks ----
  float M = NEGBIG, S = 0.f, osel = 0.f;
#pragma unroll 1
  for (int c = 0; c < 8; ++c) {
    int b0 = shsel[wid][2 * c], b1 = shsel[wid][2 * c + 1];
    int base0 = b0 * 32, base1 = b1 * 32;
    if (base0 > qpos && base1 > qpos) continue;
    int myb = (lane < 32) ? b0 : b1;
    int tok = myb * 32 + (lane & 31);
    bool ok = (tok <= qpos);
    const float4* kp = ks4 + myb * 512 + (lane & 31);
    float s = ok ? qk_dot(qr, kp) * scale : NEGBIG;
    float Mn = fmaxf(M, wave_max(s));
    float e = ok ? expf(s - Mn) : 0.f;
    float cs = wave_sum(e);
    float corr = expf(M - Mn);
    S = S * corr + cs;
    const float* v0 = vbuf + base0 * 64 + lane;
    const float* v1 = vbuf + base1 * 64 + lane;
    float a0 = 0.f, a1 = 0.f, a2 = 0.f, a3 = 0.f;
    pv16<0>(v0, e, a0, a1, a2, a3);
    pv16<16>(v0 + 1024, e, a0, a1, a2, a3);
    pv16<32>(v1, e, a0, a1, a2, a3);
    pv16<48>(v1 + 1024, e, a0, a1, a2, a3);
    osel = osel * corr + ((a0 + a1) + (a2 + a3));
    M = Mn;
  }
  osel /= S;

  // ---- sliding-window branch: aligned 32-token sub-blocks, 2 per iter ----
  float Mw = NEGBIG, Sw = 0.f, osw = 0.f;
  int kstart = qpos - 511; if (kstart < 0) kstart = 0;
  int sbf = kstart >> 5, sbl = qpos >> 5;
#pragma unroll 1
  for (int sb = sbf; sb <= sbl; sb += 2) {
    int sb1 = sb + 1;
    bool v1ok = (sb1 <= sbl);
    int sb1c = v1ok ? sb1 : sb;            // clamp for safe loads
    int myb = (lane < 32) ? sb : sb1c;
    int tok = myb * 32 + (lane & 31);
    bool ok = (tok >= kstart) && (tok <= qpos) && ((lane < 32) || v1ok);
    const float4* kp = ks4 + myb * 512 + (lane & 31);
    float s = ok ? qk_dot(qr, kp) * scale : NEGBIG;
    float Mn = fmaxf(Mw, wave_max(s));
    float e = ok ? expf(s - Mn) : 0.f;
    float cs = wave_sum(e);
    float corr = expf(Mw - Mn);
    Sw = Sw * corr + cs;
    const float* v0 = vbuf + sb * 2048 + lane;    // sb*32*64
    const float* v1 = vbuf + sb1c * 2048 + lane;
    float a0 = 0.f, a1 = 0.f, a2 = 0.f, a3 = 0.f;
    pv16<0>(v0, e, a0, a1, a2, a3);
    pv16<16>(v0 + 1024, e, a0, a1, a2, a3);
    pv16<32>(v1, e, a0, a1, a2, a3);
    pv16<48>(v1 + 1024, e, a0, a1, a2, a3);
    osw = osw * corr + ((a0 + a1) + (a2 + a3));
    Mw = Mn;
  }
  {
    float Mf = fmaxf(Mw, snk);
    float corr = expf(Mw - Mf);
    float Sf = Sw * corr + expf(snk - Mf);
    osw = osw * corr / Sf;
  }

  mixed[r * 64 + lane] = ga0 * comp_out + ga1 * osel + ga2 * osw;
}

// ---------------- launch ----------------
extern "C" void kernel_launch(void* const* d_in, const int* in_sizes, int n_in,
                              void* d_out, int out_size, void* d_ws, size_t ws_size,
                              hipStream_t stream) {
  const float* h      = (const float*)d_in[0];
  const float* w_qc   = (const float*)d_in[1];
  const float* w_qup  = (const float*)d_in[2];
  const float* w_k    = (const float*)d_in[3];
  const float* w_v    = (const float*)d_in[4];
  const float* g_qn   = (const float*)d_in[5];
  const float* g_kn   = (const float*)d_in[6];
  const float* w_gate = (const float*)d_in[7];
  const float* b_gate = (const float*)d_in[8];
  const float* sink   = (const float*)d_in[9];
  const float* wog    = (const float*)d_in[10];
  const float* w_out  = (const float*)d_in[11];
  float* out = (float*)d_out;

  float* ws = (float*)d_ws;
  float* hc  = ws;                    // 2048*256
  float* qb  = hc + 2048 * 256;       // 2048*512
  float* kb  = qb + 2048 * 512;       // 2048*64
  float* vb  = kb + 2048 * 64;        // 2048*64
  float* vc  = vb + 2048 * 64;        // 64*64
  float* mx  = vc + 64 * 64;          // 2048*512
  float* y1  = mx + 2048 * 512;       // 2048*1024
  float* kS  = y1 + 2048 * 1024;      // 2048*64 block-local K
  float* kct4 = kS + 2048 * 64;       // 16*64*4
  float* ct  = kct4 + 16 * 64 * 4;    // 2048*16 rope cos
  float* st  = ct + 2048 * 16;        // 2048*16 rope sin

  dim3 blk(256);
  dim3 blk128(128);
  rope_table_kernel<<<dim3(128), blk, 0, stream>>>(ct, st);
  // hc = h@w_qc ; kb = h@w_k ; vb = h@w_v (one dispatch, 192 blocks)
  gemm_qckv<<<dim3(6, 32), blk128, 0, stream>>>(h, w_qc, w_k, w_v, hc, kb, vb);
  // qb = hc@w_qup
  gemm_tile<<<dim3(8, 32), blk128, 0, stream>>>(hc, w_qup, qb, 2048, 512, 256, 256, 512, 512);
  // RoPE+RMSNorm q and k fused (k also emits block-local kS)
  rope_rms_fused<<<dim3(4608), blk, 0, stream>>>(qb, kb, g_qn, g_kn, kS, ct, st);
  compress_kernel<<<dim3(64), dim3(64), 0, stream>>>(kb, vb, kct4, vc);
  attn_kernel<<<dim3(4096), blk, 0, stream>>>(qb, kS, vb, kct4, vc, w_gate, b_gate, sink, mx);
  // grouped projection (dual) then output GEMM
  gemm_dual<<<dim3(16, 32), blk128, 0, stream>>>(mx, mx + 256, wog, wog + 256 * 512,
                                                 y1, y1 + 512, 256, 512, 512, 1024, 8);
  gemm_tile<<<dim3(16, 32), blk128, 0, stream>>>(y1, w_out, out, 2048, 1024, 1024, 1024, 1024, 1024);
}

// Round 22
// 428.751 us; speedup vs baseline: 1.1641x; 1.1641x over previous
//
#include <hip/hip_runtime.h>
#include <hip/hip_bf16.h>
#include <float.h>
#include <math.h>

typedef __hip_bfloat16 bf16;
typedef float v2f __attribute__((ext_vector_type(2)));

#define NEGBIG (-1e30f)

__device__ __forceinline__ float ldv(const float* p, int i) { return p[i]; }

__device__ __forceinline__ float wave_sum(float v) {
#pragma unroll
  for (int off = 32; off; off >>= 1) v += __shfl_xor(v, off, 64);
  return v;
}
__device__ __forceinline__ float wave_max(float v) {
#pragma unroll
  for (int off = 32; off; off >>= 1) v = fmaxf(v, __shfl_xor(v, off, 64));
  return v;
}

__device__ __forceinline__ float rdlane(float v, int l) {
  return __uint_as_float(__builtin_amdgcn_readlane(__float_as_uint(v), l));
}

// PV over 16 tokens: p = lanes L0..L0+15 of e (readlane -> SALU broadcast),
// V rows at vp + t*64 floats (imm offsets). 4 chains.
template <int L0>
__device__ __forceinline__ void pv16(const float* __restrict__ vp, float e,
                                     float& a0, float& a1, float& a2, float& a3) {
#pragma unroll
  for (int t = 0; t < 16; t += 4) {
    float p0 = rdlane(e, L0 + t + 0);
    float p1 = rdlane(e, L0 + t + 1);
    float p2 = rdlane(e, L0 + t + 2);
    float p3 = rdlane(e, L0 + t + 3);
    a0 += p0 * vp[(t + 0) * 64];
    a1 += p1 * vp[(t + 1) * 64];
    a2 += p2 * vp[(t + 2) * 64];
    a3 += p3 * vp[(t + 3) * 64];
  }
}

// QK dot against one 32-token K block slice, packed (v_pk_fma_f32).
__device__ __forceinline__ float qk_dot(const float4* __restrict__ qr,
                                        const float4* __restrict__ kp) {
  v2f d01 = {0.f, 0.f}, d23 = {0.f, 0.f};
#pragma unroll 1
  for (int i = 0; i < 16; i += 2) {
    float4 q0 = qr[i],     k0 = kp[i * 32];
    float4 q1 = qr[i + 1], k1 = kp[i * 32 + 32];
    d01 += (v2f){q0.x, q0.y} * (v2f){k0.x, k0.y};
    d23 += (v2f){q0.z, q0.w} * (v2f){k0.z, k0.w};
    d01 += (v2f){q1.x, q1.y} * (v2f){k1.x, k1.y};
    d23 += (v2f){q1.z, q1.w} * (v2f){k1.z, k1.w};
  }
  v2f d = d01 + d23;
  return d.x + d.y;
}

// ---------------- pipelined f32 GEMM core (r19's measured-best 4x4/256t) ----
// Double-buffered LDS, 1 barrier/K-step, b128 LDS reads, packed v_pk_fma_f32.
// (r21's 8x4/128t variant regressed ~20us -> LDS-BW was NOT the bound.)
__device__ __forceinline__ void gemm_core(
    const float* __restrict__ A, const float* __restrict__ B, float* __restrict__ C,
    int K, int lda, int ldb, int ldc, int row0, int col0)
{
  __shared__ __align__(16) float As[2][16][68];
  __shared__ __align__(16) float Bs[2][16][68];
  const int tid = threadIdx.x;
  const int tx = tid & 15, ty = tid >> 4;
  const int ar = tid >> 2;
  const int ak = (tid & 3) * 4;
  const int bk = tid >> 4;
  const int bc = (tid & 15) * 4;

  const int nk = K >> 4;
  float4 a4 = *reinterpret_cast<const float4*>(&A[(row0 + ar) * lda + ak]);
  float4 b4 = *reinterpret_cast<const float4*>(&B[bk * ldb + col0 + bc]);
  {
    As[0][ak + 0][ar] = a4.x; As[0][ak + 1][ar] = a4.y;
    As[0][ak + 2][ar] = a4.z; As[0][ak + 3][ar] = a4.w;
    *reinterpret_cast<float4*>(&Bs[0][bk][bc]) = b4;
  }

  v2f acc01[4] = {};
  v2f acc23[4] = {};
  for (int t = 0; t < nk; ++t) {
    const int cur = t & 1;
    if (t + 1 < nk) {
      int k0 = (t + 1) * 16;
      a4 = *reinterpret_cast<const float4*>(&A[(row0 + ar) * lda + k0 + ak]);
      b4 = *reinterpret_cast<const float4*>(&B[(k0 + bk) * ldb + col0 + bc]);
    }
    __syncthreads();
#pragma unroll
    for (int kk = 0; kk < 16; ++kk) {
      float4 av = *reinterpret_cast<const float4*>(&As[cur][kk][ty * 4]);
      float4 bv = *reinterpret_cast<const float4*>(&Bs[cur][kk][tx * 4]);
      v2f b01; b01.x = bv.x; b01.y = bv.y;
      v2f b23; b23.x = bv.z; b23.y = bv.w;
      float a[4] = {av.x, av.y, av.z, av.w};
#pragma unroll
      for (int i = 0; i < 4; ++i) {
        v2f as; as.x = a[i]; as.y = a[i];
        acc01[i] += as * b01;
        acc23[i] += as * b23;
      }
    }
    if (t + 1 < nk) {
      const int nxt = cur ^ 1;
      As[nxt][ak + 0][ar] = a4.x; As[nxt][ak + 1][ar] = a4.y;
      As[nxt][ak + 2][ar] = a4.z; As[nxt][ak + 3][ar] = a4.w;
      *reinterpret_cast<float4*>(&Bs[nxt][bk][bc]) = b4;
    }
  }
#pragma unroll
  for (int i = 0; i < 4; ++i) {
    float4 o = make_float4(acc01[i].x, acc01[i].y, acc23[i].x, acc23[i].y);
    *reinterpret_cast<float4*>(&C[(row0 + ty * 4 + i) * ldc + col0 + tx * 4]) = o;
  }
}

__global__ __launch_bounds__(256) void gemm_tile(
    const float* __restrict__ A, const float* __restrict__ B, float* __restrict__ C,
    int M, int N, int K, int lda, int ldb, int ldc)
{
  gemm_core(A, B, C, K, lda, ldb, ldc, blockIdx.y * 64, blockIdx.x * 64);
}

// Fused h-projections: hc (x<4), kb (x==4), vb (x==5). One dispatch, 192 blocks.
__global__ __launch_bounds__(256) void gemm_qckv(
    const float* __restrict__ h, const float* __restrict__ w_qc,
    const float* __restrict__ w_k, const float* __restrict__ w_v,
    float* __restrict__ hc, float* __restrict__ kb, float* __restrict__ vb)
{
  const int x = blockIdx.x;
  if (x < 4) {
    gemm_core(h, w_qc, hc, 1024, 1024, 256, 256, blockIdx.y * 64, x * 64);
  } else if (x == 4) {
    gemm_core(h, w_k, kb, 1024, 1024, 64, 64, blockIdx.y * 64, 0);
  } else {
    gemm_core(h, w_v, vb, 1024, 1024, 64, 64, blockIdx.y * 64, 0);
  }
}

// Fused pair of GEMMs over x-split grid: blockIdx.x < nx -> (A0,B0,C0).
__global__ __launch_bounds__(256) void gemm_dual(
    const float* __restrict__ A0, const float* __restrict__ A1,
    const float* __restrict__ B0, const float* __restrict__ B1,
    float* __restrict__ C0, float* __restrict__ C1,
    int K, int lda, int ldb, int ldc, int nx)
{
  const bool second = (int)blockIdx.x >= nx;
  const float* A = second ? A1 : A0;
  const float* B = second ? B1 : B0;
  float* C = second ? C1 : C0;
  const int bx = second ? (blockIdx.x - nx) : blockIdx.x;
  gemm_core(A, B, C, K, lda, ldb, ldc, blockIdx.y * 64, bx * 64);
}

// ---------------- RoPE cos/sin table (double trig once, f32 store) ----------
__global__ __launch_bounds__(256) void rope_table_kernel(float* __restrict__ ct,
                                                         float* __restrict__ st) {
  int tid = blockIdx.x * 256 + threadIdx.x;
  if (tid >= 2048 * 16) return;
  int pos = tid >> 4, i = tid & 15;
  double ang = (double)pos * pow(10000.0, -(double)i / 16.0);
  ct[tid] = (float)cos(ang);
  st[tid] = (float)sin(ang);
}

// ---------------- RoPE (first 32 dims) + RMSNorm (fused q+k) ----------------
__device__ __forceinline__ void rope_body(
    float* __restrict__ x, const float* __restrict__ g, int rows, int posShift,
    float* __restrict__ kS, const float* __restrict__ ct, const float* __restrict__ st,
    int bx)
{
  const int lane = threadIdx.x & 63;
  const int wid = threadIdx.x >> 6;
  const int r = bx * 4 + wid;
  if (r >= rows) return;
  const int pos = r >> posShift;
  float val = x[r * 64 + lane];
  float p = __shfl_xor(val, 16, 64);
  float out = val;
  if (lane < 32) {
    int i = lane & 15;
    float cc = ct[pos * 16 + i], ss = st[pos * 16 + i];
    out = (lane < 16) ? (val * cc - p * ss) : (p * ss + val * cc);
  }
  float ms = wave_sum(out * out) * (1.0f / 64.0f);
  float rn = rsqrtf(ms + 1e-6f);
  float res = out * rn * ldv(g, lane);
  x[r * 64 + lane] = res;
  if (kS) {
    int f4 = (r >> 5) * 512 + (lane >> 2) * 32 + (r & 31);
    kS[f4 * 4 + (lane & 3)] = res;
  }
}

__global__ __launch_bounds__(256) void rope_rms_fused(
    float* __restrict__ qx, float* __restrict__ kx,
    const float* __restrict__ gq, const float* __restrict__ gk,
    float* __restrict__ kS, const float* __restrict__ ct, const float* __restrict__ st)
{
  const int bx = blockIdx.x;
  if (bx < 4096) rope_body(qx, gq, 16384, 3, nullptr, ct, st, bx);
  else           rope_body(kx, gk, 2048, 0, kS, ct, st, bx - 4096);
}

// ---------------- block-mean compression: kcT4 (d4-major) + vc --------------
__global__ void compress_kernel(const float* __restrict__ k, const float* __restrict__ v,
                                float* __restrict__ kcT4, float* __restrict__ vc)
{
  const int n = blockIdx.x;
  const int d = threadIdx.x;
  float sk = 0.f, sv = 0.f;
  for (int j = 0; j < 32; ++j) {
    sk += k[(n * 32 + j) * 64 + d];
    sv += v[(n * 32 + j) * 64 + d];
  }
  kcT4[(d >> 2) * 256 + n * 4 + (d & 3)] = sk * (1.0f / 32.0f);
  vc[n * 64 + d] = sv * (1.0f / 32.0f);
}

// ---------------- attention: one wave per (qpos, head) — r19 form ------------
__global__ __launch_bounds__(256) void attn_kernel(
    const float* __restrict__ q, const float* __restrict__ kS, const float* __restrict__ vbuf,
    const float* __restrict__ kcT4, const float* __restrict__ vc,
    const float* __restrict__ w_gate, const float* __restrict__ b_gate,
    const float* __restrict__ sink, float* __restrict__ mixed)
{
  __shared__ __align__(16) float shq[4][64];
  __shared__ int shsel[4][16];
  const int lane = threadIdx.x & 63;
  const int wid = threadIdx.x >> 6;
  const int bid = 4095 - blockIdx.x;    // LJF: heaviest (large qpos) first
  const int r = bid * 4 + wid;          // r = qpos*8 + h
  const int qpos = r >> 3, h = r & 7;
  const float scale = 0.125f;

  float qv = q[r * 64 + lane];
  shq[wid][lane] = qv;

  // ---- gate ----
  float z0 = qv * ldv(w_gate, lane * 3 + 0);
  float z1 = qv * ldv(w_gate, lane * 3 + 1);
  float z2 = qv * ldv(w_gate, lane * 3 + 2);
  z0 = wave_sum(z0) + ldv(b_gate, 0);
  z1 = wave_sum(z1) + ldv(b_gate, 1);
  z2 = wave_sum(z2) + ldv(b_gate, 2);
  float ga0 = 1.f / (1.f + expf(-z0));
  float ga1 = 1.f / (1.f + expf(-z1));
  float ga2 = 1.f / (1.f + expf(-z2));
  float gs = fmaxf(ga0 + ga1 + ga2, 1e-6f);
  float ginv = 1.f / gs;
  ga0 *= ginv; ga1 *= ginv; ga2 *= ginv;

  const float4* qr = reinterpret_cast<const float4*>(&shq[wid][0]);
  const float4* ks4 = reinterpret_cast<const float4*>(kS);
  const float4* kct = reinterpret_cast<const float4*>(kcT4);  // [16][64]
  const float snk = ldv(sink, h);
  const int nv = (qpos + 1) >> 5;

  // ---- compressed scores (lane = block index) — scalar chains (top-k bitwise) ----
  float sc;
  {
    float d0 = 0.f, d1 = 0.f;
#pragma unroll 1
    for (int i = 0; i < 16; i += 2) {
      float4 q0 = qr[i],     k0 = kct[i * 64 + lane];
      float4 q1 = qr[i + 1], k1 = kct[(i + 1) * 64 + lane];
      d0 += q0.x * k0.x + q0.z * k0.z;
      d1 += q0.y * k0.y + q0.w * k0.w;
      d0 += q1.x * k1.x + q1.z * k1.z;
      d1 += q1.y * k1.y + q1.w * k1.w;
    }
    sc = (d0 + d1) * scale;
  }

  float comp_out = 0.f;
  if (nv > 0) {
    float scomp = (lane < nv) ? sc : NEGBIG;
    float m = fmaxf(wave_max(scomp), snk);
    float e = (lane < nv) ? expf(sc - m) : 0.f;
    float S = wave_sum(e) + expf(snk - m);
    float pn = e / S;   // zero for lane >= nv
    const float* vcp = vc + lane;
    float c0 = 0.f, c1 = 0.f, c2 = 0.f, c3 = 0.f;
    pv16<0>(vcp, pn, c0, c1, c2, c3);
    pv16<16>(vcp + 1024, pn, c0, c1, c2, c3);
    pv16<32>(vcp + 2048, pn, c0, c1, c2, c3);
    pv16<48>(vcp + 3072, pn, c0, c1, c2, c3);
    comp_out = (c0 + c1) + (c2 + c3);
  }

  // ---- top-16 block selection (jax.lax.top_k tie semantics) ----
  {
    float selv = (lane < nv) ? sc : -FLT_MAX;
#pragma unroll
    for (int it = 0; it < 16; ++it) {
      float bv = selv; int bi = lane;
#pragma unroll
      for (int off = 32; off; off >>= 1) {
        float ov = __shfl_xor(bv, off, 64);
        int oi = __shfl_xor(bi, off, 64);
        if (ov > bv || (ov == bv && oi < bi)) { bv = ov; bi = oi; }
      }
      if (lane == 0) shsel[wid][it] = bi;
      if (lane == bi) selv = -INFINITY;
    }
  }

  // ---- selected branch: 8 chunks x 2 blocks ----
  float M = NEGBIG, S = 0.f, osel = 0.f;
#pragma unroll 1
  for (int c = 0; c < 8; ++c) {
    int b0 = shsel[wid][2 * c], b1 = shsel[wid][2 * c + 1];
    int base0 = b0 * 32, base1 = b1 * 32;
    if (base0 > qpos && base1 > qpos) continue;
    int myb = (lane < 32) ? b0 : b1;
    int tok = myb * 32 + (lane & 31);
    bool ok = (tok <= qpos);
    const float4* kp = ks4 + myb * 512 + (lane & 31);
    float s = ok ? qk_dot(qr, kp) * scale : NEGBIG;
    float Mn = fmaxf(M, wave_max(s));
    float e = ok ? expf(s - Mn) : 0.f;
    float cs = wave_sum(e);
    float corr = expf(M - Mn);
    S = S * corr + cs;
    const float* v0 = vbuf + base0 * 64 + lane;
    const float* v1 = vbuf + base1 * 64 + lane;
    float a0 = 0.f, a1 = 0.f, a2 = 0.f, a3 = 0.f;
    pv16<0>(v0, e, a0, a1, a2, a3);
    pv16<16>(v0 + 1024, e, a0, a1, a2, a3);
    pv16<32>(v1, e, a0, a1, a2, a3);
    pv16<48>(v1 + 1024, e, a0, a1, a2, a3);
    osel = osel * corr + ((a0 + a1) + (a2 + a3));
    M = Mn;
  }
  osel /= S;

  // ---- sliding-window branch: aligned 32-token sub-blocks, 2 per iter ----
  float Mw = NEGBIG, Sw = 0.f, osw = 0.f;
  int kstart = qpos - 511; if (kstart < 0) kstart = 0;
  int sbf = kstart >> 5, sbl = qpos >> 5;
#pragma unroll 1
  for (int sb = sbf; sb <= sbl; sb += 2) {
    int sb1 = sb + 1;
    bool v1ok = (sb1 <= sbl);
    int sb1c = v1ok ? sb1 : sb;            // clamp for safe loads
    int myb = (lane < 32) ? sb : sb1c;
    int tok = myb * 32 + (lane & 31);
    bool ok = (tok >= kstart) && (tok <= qpos) && ((lane < 32) || v1ok);
    const float4* kp = ks4 + myb * 512 + (lane & 31);
    float s = ok ? qk_dot(qr, kp) * scale : NEGBIG;
    float Mn = fmaxf(Mw, wave_max(s));
    float e = ok ? expf(s - Mn) : 0.f;
    float cs = wave_sum(e);
    float corr = expf(Mw - Mn);
    Sw = Sw * corr + cs;
    const float* v0 = vbuf + sb * 2048 + lane;    // sb*32*64
    const float* v1 = vbuf + sb1c * 2048 + lane;
    float a0 = 0.f, a1 = 0.f, a2 = 0.f, a3 = 0.f;
    pv16<0>(v0, e, a0, a1, a2, a3);
    pv16<16>(v0 + 1024, e, a0, a1, a2, a3);
    pv16<32>(v1, e, a0, a1, a2, a3);
    pv16<48>(v1 + 1024, e, a0, a1, a2, a3);
    osw = osw * corr + ((a0 + a1) + (a2 + a3));
    Mw = Mn;
  }
  {
    float Mf = fmaxf(Mw, snk);
    float corr = expf(Mw - Mf);
    float Sf = Sw * corr + expf(snk - Mf);
    osw = osw * corr / Sf;
  }

  mixed[r * 64 + lane] = ga0 * comp_out + ga1 * osel + ga2 * osw;
}

// ---------------- launch ----------------
extern "C" void kernel_launch(void* const* d_in, const int* in_sizes, int n_in,
                              void* d_out, int out_size, void* d_ws, size_t ws_size,
                              hipStream_t stream) {
  const float* h      = (const float*)d_in[0];
  const float* w_qc   = (const float*)d_in[1];
  const float* w_qup  = (const float*)d_in[2];
  const float* w_k    = (const float*)d_in[3];
  const float* w_v    = (const float*)d_in[4];
  const float* g_qn   = (const float*)d_in[5];
  const float* g_kn   = (const float*)d_in[6];
  const float* w_gate = (const float*)d_in[7];
  const float* b_gate = (const float*)d_in[8];
  const float* sink   = (const float*)d_in[9];
  const float* wog    = (const float*)d_in[10];
  const float* w_out  = (const float*)d_in[11];
  float* out = (float*)d_out;

  float* ws = (float*)d_ws;
  float* hc  = ws;                    // 2048*256
  float* qb  = hc + 2048 * 256;       // 2048*512
  float* kb  = qb + 2048 * 512;       // 2048*64
  float* vb  = kb + 2048 * 64;        // 2048*64
  float* vc  = vb + 2048 * 64;        // 64*64
  float* mx  = vc + 64 * 64;          // 2048*512
  float* y1  = mx + 2048 * 512;       // 2048*1024
  float* kS  = y1 + 2048 * 1024;      // 2048*64 block-local K
  float* kct4 = kS + 2048 * 64;       // 16*64*4
  float* ct  = kct4 + 16 * 64 * 4;    // 2048*16 rope cos
  float* st  = ct + 2048 * 16;        // 2048*16 rope sin

  dim3 blk(256);
  rope_table_kernel<<<dim3(128), blk, 0, stream>>>(ct, st);
  // hc = h@w_qc ; kb = h@w_k ; vb = h@w_v (one dispatch, 192 blocks)
  gemm_qckv<<<dim3(6, 32), blk, 0, stream>>>(h, w_qc, w_k, w_v, hc, kb, vb);
  // qb = hc@w_qup
  gemm_tile<<<dim3(8, 32), blk, 0, stream>>>(hc, w_qup, qb, 2048, 512, 256, 256, 512, 512);
  // RoPE+RMSNorm q and k fused (k also emits block-local kS)
  rope_rms_fused<<<dim3(4608), blk, 0, stream>>>(qb, kb, g_qn, g_kn, kS, ct, st);
  compress_kernel<<<dim3(64), dim3(64), 0, stream>>>(kb, vb, kct4, vc);
  attn_kernel<<<dim3(4096), blk, 0, stream>>>(qb, kS, vb, kct4, vc, w_gate, b_gate, sink, mx);
  // grouped projection (dual) then output GEMM
  gemm_dual<<<dim3(16, 32), blk, 0, stream>>>(mx, mx + 256, wog, wog + 256 * 512,
                                              y1, y1 + 512, 256, 512, 512, 1024, 8);
  gemm_tile<<<dim3(16, 32), blk, 0, stream>>>(y1, w_out, out, 2048, 1024, 1024, 1024, 1024, 1024);
}

// Round 23
// 417.180 us; speedup vs baseline: 1.1964x; 1.0277x over previous
//
#include <hip/hip_runtime.h>
#include <hip/hip_bf16.h>
#include <float.h>
#include <math.h>

typedef __hip_bfloat16 bf16;
typedef float v2f __attribute__((ext_vector_type(2)));

#define NEGBIG (-1e30f)

__device__ __forceinline__ float ldv(const float* p, int i) { return p[i]; }

__device__ __forceinline__ float wave_sum(float v) {
#pragma unroll
  for (int off = 32; off; off >>= 1) v += __shfl_xor(v, off, 64);
  return v;
}
__device__ __forceinline__ float wave_max(float v) {
#pragma unroll
  for (int off = 32; off; off >>= 1) v = fmaxf(v, __shfl_xor(v, off, 64));
  return v;
}

__device__ __forceinline__ float rdlane(float v, int l) {
  return __uint_as_float(__builtin_amdgcn_readlane(__float_as_uint(v), l));
}

// PV over 16 tokens: p = lanes L0..L0+15 of e (readlane -> SALU broadcast),
// V rows at vp + t*64 floats (imm offsets). 4 chains. Works on global or LDS.
template <int L0>
__device__ __forceinline__ void pv16(const float* __restrict__ vp, float e,
                                     float& a0, float& a1, float& a2, float& a3) {
#pragma unroll
  for (int t = 0; t < 16; t += 4) {
    float p0 = rdlane(e, L0 + t + 0);
    float p1 = rdlane(e, L0 + t + 1);
    float p2 = rdlane(e, L0 + t + 2);
    float p3 = rdlane(e, L0 + t + 3);
    a0 += p0 * vp[(t + 0) * 64];
    a1 += p1 * vp[(t + 1) * 64];
    a2 += p2 * vp[(t + 2) * 64];
    a3 += p3 * vp[(t + 3) * 64];
  }
}

// QK dot against one 32-token K block slice, packed (v_pk_fma_f32).
__device__ __forceinline__ float qk_dot(const float4* __restrict__ qr,
                                        const float4* __restrict__ kp) {
  v2f d01 = {0.f, 0.f}, d23 = {0.f, 0.f};
#pragma unroll 1
  for (int i = 0; i < 16; i += 2) {
    float4 q0 = qr[i],     k0 = kp[i * 32];
    float4 q1 = qr[i + 1], k1 = kp[i * 32 + 32];
    d01 += (v2f){q0.x, q0.y} * (v2f){k0.x, k0.y};
    d23 += (v2f){q0.z, q0.w} * (v2f){k0.z, k0.w};
    d01 += (v2f){q1.x, q1.y} * (v2f){k1.x, k1.y};
    d23 += (v2f){q1.z, q1.w} * (v2f){k1.z, k1.w};
  }
  v2f d = d01 + d23;
  return d.x + d.y;
}

// ---------------- pipelined f32 GEMM core (measured-best 4x4/256t) ----------
__device__ __forceinline__ void gemm_core(
    const float* __restrict__ A, const float* __restrict__ B, float* __restrict__ C,
    int K, int lda, int ldb, int ldc, int row0, int col0)
{
  __shared__ __align__(16) float As[2][16][68];
  __shared__ __align__(16) float Bs[2][16][68];
  const int tid = threadIdx.x;
  const int tx = tid & 15, ty = tid >> 4;
  const int ar = tid >> 2;
  const int ak = (tid & 3) * 4;
  const int bk = tid >> 4;
  const int bc = (tid & 15) * 4;

  const int nk = K >> 4;
  float4 a4 = *reinterpret_cast<const float4*>(&A[(row0 + ar) * lda + ak]);
  float4 b4 = *reinterpret_cast<const float4*>(&B[bk * ldb + col0 + bc]);
  {
    As[0][ak + 0][ar] = a4.x; As[0][ak + 1][ar] = a4.y;
    As[0][ak + 2][ar] = a4.z; As[0][ak + 3][ar] = a4.w;
    *reinterpret_cast<float4*>(&Bs[0][bk][bc]) = b4;
  }

  v2f acc01[4] = {};
  v2f acc23[4] = {};
  for (int t = 0; t < nk; ++t) {
    const int cur = t & 1;
    if (t + 1 < nk) {
      int k0 = (t + 1) * 16;
      a4 = *reinterpret_cast<const float4*>(&A[(row0 + ar) * lda + k0 + ak]);
      b4 = *reinterpret_cast<const float4*>(&B[(k0 + bk) * ldb + col0 + bc]);
    }
    __syncthreads();
#pragma unroll
    for (int kk = 0; kk < 16; ++kk) {
      float4 av = *reinterpret_cast<const float4*>(&As[cur][kk][ty * 4]);
      float4 bv = *reinterpret_cast<const float4*>(&Bs[cur][kk][tx * 4]);
      v2f b01; b01.x = bv.x; b01.y = bv.y;
      v2f b23; b23.x = bv.z; b23.y = bv.w;
      float a[4] = {av.x, av.y, av.z, av.w};
#pragma unroll
      for (int i = 0; i < 4; ++i) {
        v2f as; as.x = a[i]; as.y = a[i];
        acc01[i] += as * b01;
        acc23[i] += as * b23;
      }
    }
    if (t + 1 < nk) {
      const int nxt = cur ^ 1;
      As[nxt][ak + 0][ar] = a4.x; As[nxt][ak + 1][ar] = a4.y;
      As[nxt][ak + 2][ar] = a4.z; As[nxt][ak + 3][ar] = a4.w;
      *reinterpret_cast<float4*>(&Bs[nxt][bk][bc]) = b4;
    }
  }
#pragma unroll
  for (int i = 0; i < 4; ++i) {
    float4 o = make_float4(acc01[i].x, acc01[i].y, acc23[i].x, acc23[i].y);
    *reinterpret_cast<float4*>(&C[(row0 + ty * 4 + i) * ldc + col0 + tx * 4]) = o;
  }
}

__global__ __launch_bounds__(256) void gemm_tile(
    const float* __restrict__ A, const float* __restrict__ B, float* __restrict__ C,
    int M, int N, int K, int lda, int ldb, int ldc)
{
  gemm_core(A, B, C, K, lda, ldb, ldc, blockIdx.y * 64, blockIdx.x * 64);
}

// Fused h-projections: hc (x<4), kb (x==4), vb (x==5). One dispatch, 192 blocks.
__global__ __launch_bounds__(256) void gemm_qckv(
    const float* __restrict__ h, const float* __restrict__ w_qc,
    const float* __restrict__ w_k, const float* __restrict__ w_v,
    float* __restrict__ hc, float* __restrict__ kb, float* __restrict__ vb)
{
  const int x = blockIdx.x;
  if (x < 4) {
    gemm_core(h, w_qc, hc, 1024, 1024, 256, 256, blockIdx.y * 64, x * 64);
  } else if (x == 4) {
    gemm_core(h, w_k, kb, 1024, 1024, 64, 64, blockIdx.y * 64, 0);
  } else {
    gemm_core(h, w_v, vb, 1024, 1024, 64, 64, blockIdx.y * 64, 0);
  }
}

// Fused pair of GEMMs over x-split grid: blockIdx.x < nx -> (A0,B0,C0).
__global__ __launch_bounds__(256) void gemm_dual(
    const float* __restrict__ A0, const float* __restrict__ A1,
    const float* __restrict__ B0, const float* __restrict__ B1,
    float* __restrict__ C0, float* __restrict__ C1,
    int K, int lda, int ldb, int ldc, int nx)
{
  const bool second = (int)blockIdx.x >= nx;
  const float* A = second ? A1 : A0;
  const float* B = second ? B1 : B0;
  float* C = second ? C1 : C0;
  const int bx = second ? (blockIdx.x - nx) : blockIdx.x;
  gemm_core(A, B, C, K, lda, ldb, ldc, blockIdx.y * 64, bx * 64);
}

// ---------------- RoPE cos/sin table (double trig once, f32 store) ----------
__global__ __launch_bounds__(256) void rope_table_kernel(float* __restrict__ ct,
                                                         float* __restrict__ st) {
  int tid = blockIdx.x * 256 + threadIdx.x;
  if (tid >= 2048 * 16) return;
  int pos = tid >> 4, i = tid & 15;
  double ang = (double)pos * pow(10000.0, -(double)i / 16.0);
  ct[tid] = (float)cos(ang);
  st[tid] = (float)sin(ang);
}

// ---------------- RoPE (first 32 dims) + RMSNorm (fused q+k) ----------------
__device__ __forceinline__ void rope_body(
    float* __restrict__ x, const float* __restrict__ g, int rows, int posShift,
    float* __restrict__ kS, const float* __restrict__ ct, const float* __restrict__ st,
    int bx)
{
  const int lane = threadIdx.x & 63;
  const int wid = threadIdx.x >> 6;
  const int r = bx * 4 + wid;
  if (r >= rows) return;
  const int pos = r >> posShift;
  float val = x[r * 64 + lane];
  float p = __shfl_xor(val, 16, 64);
  float out = val;
  if (lane < 32) {
    int i = lane & 15;
    float cc = ct[pos * 16 + i], ss = st[pos * 16 + i];
    out = (lane < 16) ? (val * cc - p * ss) : (p * ss + val * cc);
  }
  float ms = wave_sum(out * out) * (1.0f / 64.0f);
  float rn = rsqrtf(ms + 1e-6f);
  float res = out * rn * ldv(g, lane);
  x[r * 64 + lane] = res;
  if (kS) {
    int f4 = (r >> 5) * 512 + (lane >> 2) * 32 + (r & 31);
    kS[f4 * 4 + (lane & 3)] = res;
  }
}

__global__ __launch_bounds__(256) void rope_rms_fused(
    float* __restrict__ qx, float* __restrict__ kx,
    const float* __restrict__ gq, const float* __restrict__ gk,
    float* __restrict__ kS, const float* __restrict__ ct, const float* __restrict__ st)
{
  const int bx = blockIdx.x;
  if (bx < 4096) rope_body(qx, gq, 16384, 3, nullptr, ct, st, bx);
  else           rope_body(kx, gk, 2048, 0, kS, ct, st, bx - 4096);
}

// ---------------- block-mean compression: kcT4 (d4-major) + vc --------------
__global__ void compress_kernel(const float* __restrict__ k, const float* __restrict__ v,
                                float* __restrict__ kcT4, float* __restrict__ vc)
{
  const int n = blockIdx.x;
  const int d = threadIdx.x;
  float sk = 0.f, sv = 0.f;
  for (int j = 0; j < 32; ++j) {
    sk += k[(n * 32 + j) * 64 + d];
    sv += v[(n * 32 + j) * 64 + d];
  }
  kcT4[(d >> 2) * 256 + n * 4 + (d & 3)] = sk * (1.0f / 32.0f);
  vc[n * 64 + d] = sv * (1.0f / 32.0f);
}

// ---------------- attention: 8 waves (= 8 heads) per qpos block --------------
// r22 analysis: attn pinned at ~298us == L2-BW roofline (~9GB reads / 34.5TB/s).
// All 8 heads of one qpos share window K/V -> stage window chunks in LDS,
// cutting window L2 traffic 8x. Phase 1 (comp/top-k/sel) per-wave, unchanged.
// Compute values/order identical -> absmax bitwise-unchanged.
__global__ __launch_bounds__(512) void attn_kernel(
    const float* __restrict__ q, const float* __restrict__ kS, const float* __restrict__ vbuf,
    const float* __restrict__ kcT4, const float* __restrict__ vc,
    const float* __restrict__ w_gate, const float* __restrict__ b_gate,
    const float* __restrict__ sink, float* __restrict__ mixed)
{
  __shared__ __align__(16) float4 stgK[1024];   // 16 KB: 2 blocks x [d4=16][tok=32]
  __shared__ __align__(16) float stgV[4096];    // 16 KB: [row=64][d=64]
  __shared__ __align__(16) float shq[8][64];
  __shared__ int shsel[8][16];
  const int tid = threadIdx.x;
  const int lane = tid & 63;
  const int wid = tid >> 6;             // head h = wid
  const int qpos = 2047 - blockIdx.x;   // LJF: heaviest first
  const int h = wid;
  const int r = qpos * 8 + h;
  const float scale = 0.125f;

  float qv = q[r * 64 + lane];
  shq[wid][lane] = qv;

  // ---- gate ----
  float z0 = qv * ldv(w_gate, lane * 3 + 0);
  float z1 = qv * ldv(w_gate, lane * 3 + 1);
  float z2 = qv * ldv(w_gate, lane * 3 + 2);
  z0 = wave_sum(z0) + ldv(b_gate, 0);
  z1 = wave_sum(z1) + ldv(b_gate, 1);
  z2 = wave_sum(z2) + ldv(b_gate, 2);
  float ga0 = 1.f / (1.f + expf(-z0));
  float ga1 = 1.f / (1.f + expf(-z1));
  float ga2 = 1.f / (1.f + expf(-z2));
  float gs = fmaxf(ga0 + ga1 + ga2, 1e-6f);
  float ginv = 1.f / gs;
  ga0 *= ginv; ga1 *= ginv; ga2 *= ginv;

  const float4* qr = reinterpret_cast<const float4*>(&shq[wid][0]);
  const float4* ks4 = reinterpret_cast<const float4*>(kS);
  const float4* kct = reinterpret_cast<const float4*>(kcT4);  // [16][64]
  const float snk = ldv(sink, h);
  const int nv = (qpos + 1) >> 5;

  // ======== PHASE 1: per-wave (no barriers): comp + top-k + selected ========

  // ---- compressed scores (lane = block index) — scalar chains (top-k bitwise) ----
  float sc;
  {
    float d0 = 0.f, d1 = 0.f;
#pragma unroll 1
    for (int i = 0; i < 16; i += 2) {
      float4 q0 = qr[i],     k0 = kct[i * 64 + lane];
      float4 q1 = qr[i + 1], k1 = kct[(i + 1) * 64 + lane];
      d0 += q0.x * k0.x + q0.z * k0.z;
      d1 += q0.y * k0.y + q0.w * k0.w;
      d0 += q1.x * k1.x + q1.z * k1.z;
      d1 += q1.y * k1.y + q1.w * k1.w;
    }
    sc = (d0 + d1) * scale;
  }

  float comp_out = 0.f;
  if (nv > 0) {
    float scomp = (lane < nv) ? sc : NEGBIG;
    float m = fmaxf(wave_max(scomp), snk);
    float e = (lane < nv) ? expf(sc - m) : 0.f;
    float S = wave_sum(e) + expf(snk - m);
    float pn = e / S;   // zero for lane >= nv
    const float* vcp = vc + lane;
    float c0 = 0.f, c1 = 0.f, c2 = 0.f, c3 = 0.f;
    pv16<0>(vcp, pn, c0, c1, c2, c3);
    pv16<16>(vcp + 1024, pn, c0, c1, c2, c3);
    pv16<32>(vcp + 2048, pn, c0, c1, c2, c3);
    pv16<48>(vcp + 3072, pn, c0, c1, c2, c3);
    comp_out = (c0 + c1) + (c2 + c3);
  }

  // ---- top-16 block selection (jax.lax.top_k tie semantics) ----
  {
    float selv = (lane < nv) ? sc : -FLT_MAX;
#pragma unroll
    for (int it = 0; it < 16; ++it) {
      float bv = selv; int bi = lane;
#pragma unroll
      for (int off = 32; off; off >>= 1) {
        float ov = __shfl_xor(bv, off, 64);
        int oi = __shfl_xor(bi, off, 64);
        if (ov > bv || (ov == bv && oi < bi)) { bv = ov; bi = oi; }
      }
      if (lane == 0) shsel[wid][it] = bi;
      if (lane == bi) selv = -INFINITY;
    }
  }

  // ---- selected branch: 8 chunks x 2 blocks (global reads, per-head) ----
  float M = NEGBIG, S = 0.f, osel = 0.f;
#pragma unroll 1
  for (int c = 0; c < 8; ++c) {
    int b0 = shsel[wid][2 * c], b1 = shsel[wid][2 * c + 1];
    int base0 = b0 * 32, base1 = b1 * 32;
    if (base0 > qpos && base1 > qpos) continue;
    int myb = (lane < 32) ? b0 : b1;
    int tok = myb * 32 + (lane & 31);
    bool ok = (tok <= qpos);
    const float4* kp = ks4 + myb * 512 + (lane & 31);
    float s = ok ? qk_dot(qr, kp) * scale : NEGBIG;
    float Mn = fmaxf(M, wave_max(s));
    float e = ok ? expf(s - Mn) : 0.f;
    float cs = wave_sum(e);
    float corr = expf(M - Mn);
    S = S * corr + cs;
    const float* v0 = vbuf + base0 * 64 + lane;
    const float* v1 = vbuf + base1 * 64 + lane;
    float a0 = 0.f, a1 = 0.f, a2 = 0.f, a3 = 0.f;
    pv16<0>(v0, e, a0, a1, a2, a3);
    pv16<16>(v0 + 1024, e, a0, a1, a2, a3);
    pv16<32>(v1, e, a0, a1, a2, a3);
    pv16<48>(v1 + 1024, e, a0, a1, a2, a3);
    osel = osel * corr + ((a0 + a1) + (a2 + a3));
    M = Mn;
  }
  osel /= S;

  // ======== PHASE 2: window with cooperative LDS staging (8-way reuse) ======
  float Mw = NEGBIG, Sw = 0.f, osw = 0.f;
  int kstart = qpos - 511; if (kstart < 0) kstart = 0;
  int sbf = kstart >> 5, sbl = qpos >> 5;   // same for all 8 waves (same qpos)
  const float4* vbuf4 = reinterpret_cast<const float4*>(vbuf);
#pragma unroll 1
  for (int sb = sbf; sb <= sbl; sb += 2) {
    int sb1 = sb + 1;
    bool v1ok = (sb1 <= sbl);
    int sb1c = v1ok ? sb1 : sb;            // clamp for safe loads
    __syncthreads();   // previous chunk's LDS reads complete
    // stage K: 1024 f4 (block sb at [0,512), sb1c at [512,1024))
#pragma unroll
    for (int j = 0; j < 2; ++j) {
      int g = j * 512 + tid;
      int blk = (g >> 9) ? sb1c : sb;
      stgK[g] = ks4[blk * 512 + (g & 511)];
    }
    // stage V: 1024 f4 = 64 rows x 16 f4 (rows 0-31: sb, 32-63: sb1c)
#pragma unroll
    for (int j = 0; j < 2; ++j) {
      int g = j * 512 + tid;
      int row = g >> 4;
      int srow = (row < 32) ? (sb * 32 + row) : (sb1c * 32 + (row - 32));
      reinterpret_cast<float4*>(stgV)[g] = vbuf4[srow * 16 + (g & 15)];
    }
    __syncthreads();   // staging visible
    int myoff = (lane < 32) ? 0 : 512;
    int tok = ((lane < 32) ? sb : sb1c) * 32 + (lane & 31);
    bool ok = (tok >= kstart) && (tok <= qpos) && ((lane < 32) || v1ok);
    const float4* kp = stgK + myoff + (lane & 31);
    float s = ok ? qk_dot(qr, kp) * scale : NEGBIG;
    float Mn = fmaxf(Mw, wave_max(s));
    float e = ok ? expf(s - Mn) : 0.f;
    float cs = wave_sum(e);
    float corr = expf(Mw - Mn);
    Sw = Sw * corr + cs;
    const float* v0 = stgV + lane;          // rows 0..31 (block sb)
    const float* v1 = stgV + 2048 + lane;   // rows 32..63 (block sb1c)
    float a0 = 0.f, a1 = 0.f, a2 = 0.f, a3 = 0.f;
    pv16<0>(v0, e, a0, a1, a2, a3);
    pv16<16>(v0 + 1024, e, a0, a1, a2, a3);
    pv16<32>(v1, e, a0, a1, a2, a3);
    pv16<48>(v1 + 1024, e, a0, a1, a2, a3);
    osw = osw * corr + ((a0 + a1) + (a2 + a3));
    Mw = Mn;
  }
  {
    float Mf = fmaxf(Mw, snk);
    float corr = expf(Mw - Mf);
    float Sf = Sw * corr + expf(snk - Mf);
    osw = osw * corr / Sf;
  }

  mixed[r * 64 + lane] = ga0 * comp_out + ga1 * osel + ga2 * osw;
}

// ---------------- launch ----------------
extern "C" void kernel_launch(void* const* d_in, const int* in_sizes, int n_in,
                              void* d_out, int out_size, void* d_ws, size_t ws_size,
                              hipStream_t stream) {
  const float* h      = (const float*)d_in[0];
  const float* w_qc   = (const float*)d_in[1];
  const float* w_qup  = (const float*)d_in[2];
  const float* w_k    = (const float*)d_in[3];
  const float* w_v    = (const float*)d_in[4];
  const float* g_qn   = (const float*)d_in[5];
  const float* g_kn   = (const float*)d_in[6];
  const float* w_gate = (const float*)d_in[7];
  const float* b_gate = (const float*)d_in[8];
  const float* sink   = (const float*)d_in[9];
  const float* wog    = (const float*)d_in[10];
  const float* w_out  = (const float*)d_in[11];
  float* out = (float*)d_out;

  float* ws = (float*)d_ws;
  float* hc  = ws;                    // 2048*256
  float* qb  = hc + 2048 * 256;       // 2048*512
  float* kb  = qb + 2048 * 512;       // 2048*64
  float* vb  = kb + 2048 * 64;        // 2048*64
  float* vc  = vb + 2048 * 64;        // 64*64
  float* mx  = vc + 64 * 64;          // 2048*512
  float* y1  = mx + 2048 * 512;       // 2048*1024
  float* kS  = y1 + 2048 * 1024;      // 2048*64 block-local K
  float* kct4 = kS + 2048 * 64;       // 16*64*4
  float* ct  = kct4 + 16 * 64 * 4;    // 2048*16 rope cos
  float* st  = ct + 2048 * 16;        // 2048*16 rope sin

  dim3 blk(256);
  rope_table_kernel<<<dim3(128), blk, 0, stream>>>(ct, st);
  // hc = h@w_qc ; kb = h@w_k ; vb = h@w_v (one dispatch, 192 blocks)
  gemm_qckv<<<dim3(6, 32), blk, 0, stream>>>(h, w_qc, w_k, w_v, hc, kb, vb);
  // qb = hc@w_qup
  gemm_tile<<<dim3(8, 32), blk, 0, stream>>>(hc, w_qup, qb, 2048, 512, 256, 256, 512, 512);
  // RoPE+RMSNorm q and k fused (k also emits block-local kS)
  rope_rms_fused<<<dim3(4608), blk, 0, stream>>>(qb, kb, g_qn, g_kn, kS, ct, st);
  compress_kernel<<<dim3(64), dim3(64), 0, stream>>>(kb, vb, kct4, vc);
  // attention: 2048 blocks x 512 threads (8 heads share one qpos's window)
  attn_kernel<<<dim3(2048), dim3(512), 0, stream>>>(qb, kS, vb, kct4, vc, w_gate, b_gate, sink, mx);
  // grouped projection (dual) then output GEMM
  gemm_dual<<<dim3(16, 32), blk, 0, stream>>>(mx, mx + 256, wog, wog + 256 * 512,
                                              y1, y1 + 512, 256, 512, 512, 1024, 8);
  gemm_tile<<<dim3(16, 32), blk, 0, stream>>>(y1, w_out, out, 2048, 1024, 1024, 1024, 1024, 1024);
}

// Round 24
// 399.483 us; speedup vs baseline: 1.2494x; 1.0443x over previous
//
#include <hip/hip_runtime.h>
#include <hip/hip_bf16.h>
#include <float.h>
#include <math.h>

typedef __hip_bfloat16 bf16;
typedef float v2f __attribute__((ext_vector_type(2)));
typedef float f32x4 __attribute__((ext_vector_type(4)));
typedef short bf16x8 __attribute__((ext_vector_type(8)));

#define NEGBIG (-1e30f)

__device__ __forceinline__ float ldv(const float* p, int i) { return p[i]; }

// RNE f32 -> bf16 (bit pattern), matches HW rounding.
__device__ __forceinline__ unsigned short f2bf(float x) {
  unsigned u = __float_as_uint(x);
  u += 0x7FFFu + ((u >> 16) & 1u);
  return (unsigned short)(u >> 16);
}

__device__ __forceinline__ float wave_sum(float v) {
#pragma unroll
  for (int off = 32; off; off >>= 1) v += __shfl_xor(v, off, 64);
  return v;
}
__device__ __forceinline__ float wave_max(float v) {
#pragma unroll
  for (int off = 32; off; off >>= 1) v = fmaxf(v, __shfl_xor(v, off, 64));
  return v;
}

__device__ __forceinline__ float rdlane(float v, int l) {
  return __uint_as_float(__builtin_amdgcn_readlane(__float_as_uint(v), l));
}

// PV over 16 tokens (readlane broadcast, imm-offset V rows). 4 chains.
template <int L0>
__device__ __forceinline__ void pv16(const float* __restrict__ vp, float e,
                                     float& a0, float& a1, float& a2, float& a3) {
#pragma unroll
  for (int t = 0; t < 16; t += 4) {
    float p0 = rdlane(e, L0 + t + 0);
    float p1 = rdlane(e, L0 + t + 1);
    float p2 = rdlane(e, L0 + t + 2);
    float p3 = rdlane(e, L0 + t + 3);
    a0 += p0 * vp[(t + 0) * 64];
    a1 += p1 * vp[(t + 1) * 64];
    a2 += p2 * vp[(t + 2) * 64];
    a3 += p3 * vp[(t + 3) * 64];
  }
}

// QK dot against one 32-token K block slice, packed (v_pk_fma_f32).
__device__ __forceinline__ float qk_dot(const float4* __restrict__ qr,
                                        const float4* __restrict__ kp) {
  v2f d01 = {0.f, 0.f}, d23 = {0.f, 0.f};
#pragma unroll 1
  for (int i = 0; i < 16; i += 2) {
    float4 q0 = qr[i],     k0 = kp[i * 32];
    float4 q1 = qr[i + 1], k1 = kp[i * 32 + 32];
    d01 += (v2f){q0.x, q0.y} * (v2f){k0.x, k0.y};
    d23 += (v2f){q0.z, q0.w} * (v2f){k0.z, k0.w};
    d01 += (v2f){q1.x, q1.y} * (v2f){k1.x, k1.y};
    d23 += (v2f){q1.z, q1.w} * (v2f){k1.z, k1.w};
  }
  v2f d = d01 + d23;
  return d.x + d.y;
}

// ---------------- pipelined f32 GEMM core (measured-best 4x4/256t) ----------
// BF16OUT: store accumulators as bf16 (RNE) instead of f32.
template <bool BF16OUT>
__device__ __forceinline__ void gemm_core_t(
    const float* __restrict__ A, const float* __restrict__ B, void* __restrict__ Cv,
    int K, int lda, int ldb, int ldc, int row0, int col0)
{
  __shared__ __align__(16) float As[2][16][68];
  __shared__ __align__(16) float Bs[2][16][68];
  const int tid = threadIdx.x;
  const int tx = tid & 15, ty = tid >> 4;
  const int ar = tid >> 2;
  const int ak = (tid & 3) * 4;
  const int bk = tid >> 4;
  const int bc = (tid & 15) * 4;

  const int nk = K >> 4;
  float4 a4 = *reinterpret_cast<const float4*>(&A[(row0 + ar) * lda + ak]);
  float4 b4 = *reinterpret_cast<const float4*>(&B[bk * ldb + col0 + bc]);
  {
    As[0][ak + 0][ar] = a4.x; As[0][ak + 1][ar] = a4.y;
    As[0][ak + 2][ar] = a4.z; As[0][ak + 3][ar] = a4.w;
    *reinterpret_cast<float4*>(&Bs[0][bk][bc]) = b4;
  }

  v2f acc01[4] = {};
  v2f acc23[4] = {};
  for (int t = 0; t < nk; ++t) {
    const int cur = t & 1;
    if (t + 1 < nk) {
      int k0 = (t + 1) * 16;
      a4 = *reinterpret_cast<const float4*>(&A[(row0 + ar) * lda + k0 + ak]);
      b4 = *reinterpret_cast<const float4*>(&B[(k0 + bk) * ldb + col0 + bc]);
    }
    __syncthreads();
#pragma unroll
    for (int kk = 0; kk < 16; ++kk) {
      float4 av = *reinterpret_cast<const float4*>(&As[cur][kk][ty * 4]);
      float4 bv = *reinterpret_cast<const float4*>(&Bs[cur][kk][tx * 4]);
      v2f b01; b01.x = bv.x; b01.y = bv.y;
      v2f b23; b23.x = bv.z; b23.y = bv.w;
      float a[4] = {av.x, av.y, av.z, av.w};
#pragma unroll
      for (int i = 0; i < 4; ++i) {
        v2f as; as.x = a[i]; as.y = a[i];
        acc01[i] += as * b01;
        acc23[i] += as * b23;
      }
    }
    if (t + 1 < nk) {
      const int nxt = cur ^ 1;
      As[nxt][ak + 0][ar] = a4.x; As[nxt][ak + 1][ar] = a4.y;
      As[nxt][ak + 2][ar] = a4.z; As[nxt][ak + 3][ar] = a4.w;
      *reinterpret_cast<float4*>(&Bs[nxt][bk][bc]) = b4;
    }
  }
#pragma unroll
  for (int i = 0; i < 4; ++i) {
    if (BF16OUT) {
      unsigned short h0 = f2bf(acc01[i].x), h1 = f2bf(acc01[i].y);
      unsigned short h2 = f2bf(acc23[i].x), h3 = f2bf(acc23[i].y);
      uint2 pk;
      pk.x = (unsigned)h0 | ((unsigned)h1 << 16);
      pk.y = (unsigned)h2 | ((unsigned)h3 << 16);
      unsigned short* C = (unsigned short*)Cv;
      *reinterpret_cast<uint2*>(&C[(row0 + ty * 4 + i) * ldc + col0 + tx * 4]) = pk;
    } else {
      float* C = (float*)Cv;
      float4 o = make_float4(acc01[i].x, acc01[i].y, acc23[i].x, acc23[i].y);
      *reinterpret_cast<float4*>(&C[(row0 + ty * 4 + i) * ldc + col0 + tx * 4]) = o;
    }
  }
}

__global__ __launch_bounds__(256) void gemm_tile(
    const float* __restrict__ A, const float* __restrict__ B, float* __restrict__ C,
    int M, int N, int K, int lda, int ldb, int ldc)
{
  gemm_core_t<false>(A, B, C, K, lda, ldb, ldc, blockIdx.y * 64, blockIdx.x * 64);
}

// Fused h-projections: hc (x<4), kb (x==4), vb (x==5). One dispatch, 192 blocks.
__global__ __launch_bounds__(256) void gemm_qckv(
    const float* __restrict__ h, const float* __restrict__ w_qc,
    const float* __restrict__ w_k, const float* __restrict__ w_v,
    float* __restrict__ hc, float* __restrict__ kb, float* __restrict__ vb)
{
  const int x = blockIdx.x;
  if (x < 4) {
    gemm_core_t<false>(h, w_qc, hc, 1024, 1024, 256, 256, blockIdx.y * 64, x * 64);
  } else if (x == 4) {
    gemm_core_t<false>(h, w_k, kb, 1024, 1024, 64, 64, blockIdx.y * 64, 0);
  } else {
    gemm_core_t<false>(h, w_v, vb, 1024, 1024, 64, 64, blockIdx.y * 64, 0);
  }
}

// Fused pair of GEMMs, bf16 output (feeds the MFMA out-GEMM).
__global__ __launch_bounds__(256) void gemm_dual_b16(
    const float* __restrict__ A0, const float* __restrict__ A1,
    const float* __restrict__ B0, const float* __restrict__ B1,
    unsigned short* __restrict__ C0, unsigned short* __restrict__ C1,
    int K, int lda, int ldb, int ldc, int nx)
{
  const bool second = (int)blockIdx.x >= nx;
  const float* A = second ? A1 : A0;
  const float* B = second ? B1 : B0;
  unsigned short* C = second ? C1 : C0;
  const int bx = second ? (blockIdx.x - nx) : blockIdx.x;
  gemm_core_t<true>(A, B, C, K, lda, ldb, ldc, blockIdx.y * 64, bx * 64);
}

// Transpose+convert w_out (1024x1024 f32, row-major [k][col]) -> wT bf16 [col][k].
__global__ __launch_bounds__(256) void wtrans_kernel(
    const float* __restrict__ w, unsigned short* __restrict__ wT)
{
  int gid = blockIdx.x * 256 + threadIdx.x;   // 1M threads
  int k = gid >> 10, col = gid & 1023;
  wT[col * 1024 + k] = f2bf(w[k * 1024 + col]);
}

// ---------------- MFMA bf16 out-GEMM: out[2048x1024] = y1b @ wT^T ----------
// 4 waves/block; wave w computes rows [by*64+w*16, +16) x cols [bx*64, +64)
// as 4 n-tiles of 16x16x(K=1024) via v_mfma_f32_16x16x32_bf16.
// Layouts (guide §3, HW-verified): A row=lane&15, k=(lane>>4)*8+i;
// B col=lane&15, same k; C/D col=lane&15, row=(lane>>4)*4+reg.
__global__ __launch_bounds__(256) void gemm_out_mfma(
    const unsigned short* __restrict__ y1b, const unsigned short* __restrict__ wT,
    float* __restrict__ out)
{
  const int lane = threadIdx.x & 63;
  const int wid = threadIdx.x >> 6;
  const int rowbase = blockIdx.y * 64 + wid * 16;
  const int colbase = blockIdx.x * 64;
  const int rc = lane & 15;
  const int kg = lane >> 4;            // k-group 0..3
  const unsigned short* ap = y1b + (rowbase + rc) * 1024 + kg * 8;
  const unsigned short* bp = wT + (colbase + rc) * 1024 + kg * 8;

  f32x4 acc0 = {0.f, 0.f, 0.f, 0.f};
  f32x4 acc1 = {0.f, 0.f, 0.f, 0.f};
  f32x4 acc2 = {0.f, 0.f, 0.f, 0.f};
  f32x4 acc3 = {0.f, 0.f, 0.f, 0.f};
#pragma unroll 2
  for (int k0 = 0; k0 < 1024; k0 += 32) {
    bf16x8 a = *reinterpret_cast<const bf16x8*>(ap + k0);
    bf16x8 b0 = *reinterpret_cast<const bf16x8*>(bp + k0);
    bf16x8 b1 = *reinterpret_cast<const bf16x8*>(bp + 16 * 1024 + k0);
    bf16x8 b2 = *reinterpret_cast<const bf16x8*>(bp + 32 * 1024 + k0);
    bf16x8 b3 = *reinterpret_cast<const bf16x8*>(bp + 48 * 1024 + k0);
    acc0 = __builtin_amdgcn_mfma_f32_16x16x32_bf16(a, b0, acc0, 0, 0, 0);
    acc1 = __builtin_amdgcn_mfma_f32_16x16x32_bf16(a, b1, acc1, 0, 0, 0);
    acc2 = __builtin_amdgcn_mfma_f32_16x16x32_bf16(a, b2, acc2, 0, 0, 0);
    acc3 = __builtin_amdgcn_mfma_f32_16x16x32_bf16(a, b3, acc3, 0, 0, 0);
  }
  // C/D: col = lane&15, row = kg*4 + j
#pragma unroll
  for (int j = 0; j < 4; ++j) {
    int row = rowbase + kg * 4 + j;
    out[row * 1024 + colbase + rc]      = acc0[j];
    out[row * 1024 + colbase + 16 + rc] = acc1[j];
    out[row * 1024 + colbase + 32 + rc] = acc2[j];
    out[row * 1024 + colbase + 48 + rc] = acc3[j];
  }
}

// ---------------- RoPE cos/sin table (double trig once, f32 store) ----------
__global__ __launch_bounds__(256) void rope_table_kernel(float* __restrict__ ct,
                                                         float* __restrict__ st) {
  int tid = blockIdx.x * 256 + threadIdx.x;
  if (tid >= 2048 * 16) return;
  int pos = tid >> 4, i = tid & 15;
  double ang = (double)pos * pow(10000.0, -(double)i / 16.0);
  ct[tid] = (float)cos(ang);
  st[tid] = (float)sin(ang);
}

// ---------------- RoPE (first 32 dims) + RMSNorm (fused q+k) ----------------
__device__ __forceinline__ void rope_body(
    float* __restrict__ x, const float* __restrict__ g, int rows, int posShift,
    float* __restrict__ kS, const float* __restrict__ ct, const float* __restrict__ st,
    int bx)
{
  const int lane = threadIdx.x & 63;
  const int wid = threadIdx.x >> 6;
  const int r = bx * 4 + wid;
  if (r >= rows) return;
  const int pos = r >> posShift;
  float val = x[r * 64 + lane];
  float p = __shfl_xor(val, 16, 64);
  float out = val;
  if (lane < 32) {
    int i = lane & 15;
    float cc = ct[pos * 16 + i], ss = st[pos * 16 + i];
    out = (lane < 16) ? (val * cc - p * ss) : (p * ss + val * cc);
  }
  float ms = wave_sum(out * out) * (1.0f / 64.0f);
  float rn = rsqrtf(ms + 1e-6f);
  float res = out * rn * ldv(g, lane);
  x[r * 64 + lane] = res;
  if (kS) {
    int f4 = (r >> 5) * 512 + (lane >> 2) * 32 + (r & 31);
    kS[f4 * 4 + (lane & 3)] = res;
  }
}

__global__ __launch_bounds__(256) void rope_rms_fused(
    float* __restrict__ qx, float* __restrict__ kx,
    const float* __restrict__ gq, const float* __restrict__ gk,
    float* __restrict__ kS, const float* __restrict__ ct, const float* __restrict__ st)
{
  const int bx = blockIdx.x;
  if (bx < 4096) rope_body(qx, gq, 16384, 3, nullptr, ct, st, bx);
  else           rope_body(kx, gk, 2048, 0, kS, ct, st, bx - 4096);
}

// ---------------- block-mean compression: kcT4 (d4-major) + vc --------------
__global__ void compress_kernel(const float* __restrict__ k, const float* __restrict__ v,
                                float* __restrict__ kcT4, float* __restrict__ vc)
{
  const int n = blockIdx.x;
  const int d = threadIdx.x;
  float sk = 0.f, sv = 0.f;
  for (int j = 0; j < 32; ++j) {
    sk += k[(n * 32 + j) * 64 + d];
    sv += v[(n * 32 + j) * 64 + d];
  }
  kcT4[(d >> 2) * 256 + n * 4 + (d & 3)] = sk * (1.0f / 32.0f);
  vc[n * 64 + d] = sv * (1.0f / 32.0f);
}

// ---------------- attention: 8 waves (= 8 heads) per qpos block (r23) -------
__global__ __launch_bounds__(512) void attn_kernel(
    const float* __restrict__ q, const float* __restrict__ kS, const float* __restrict__ vbuf,
    const float* __restrict__ kcT4, const float* __restrict__ vc,
    const float* __restrict__ w_gate, const float* __restrict__ b_gate,
    const float* __restrict__ sink, float* __restrict__ mixed)
{
  __shared__ __align__(16) float4 stgK[1024];
  __shared__ __align__(16) float stgV[4096];
  __shared__ __align__(16) float shq[8][64];
  __shared__ int shsel[8][16];
  const int tid = threadIdx.x;
  const int lane = tid & 63;
  const int wid = tid >> 6;
  const int qpos = 2047 - blockIdx.x;
  const int h = wid;
  const int r = qpos * 8 + h;
  const float scale = 0.125f;

  float qv = q[r * 64 + lane];
  shq[wid][lane] = qv;

  // ---- gate ----
  float z0 = qv * ldv(w_gate, lane * 3 + 0);
  float z1 = qv * ldv(w_gate, lane * 3 + 1);
  float z2 = qv * ldv(w_gate, lane * 3 + 2);
  z0 = wave_sum(z0) + ldv(b_gate, 0);
  z1 = wave_sum(z1) + ldv(b_gate, 1);
  z2 = wave_sum(z2) + ldv(b_gate, 2);
  float ga0 = 1.f / (1.f + expf(-z0));
  float ga1 = 1.f / (1.f + expf(-z1));
  float ga2 = 1.f / (1.f + expf(-z2));
  float gs = fmaxf(ga0 + ga1 + ga2, 1e-6f);
  float ginv = 1.f / gs;
  ga0 *= ginv; ga1 *= ginv; ga2 *= ginv;

  const float4* qr = reinterpret_cast<const float4*>(&shq[wid][0]);
  const float4* ks4 = reinterpret_cast<const float4*>(kS);
  const float4* kct = reinterpret_cast<const float4*>(kcT4);
  const float snk = ldv(sink, h);
  const int nv = (qpos + 1) >> 5;

  // ======== PHASE 1: per-wave: comp + top-k + selected ========
  float sc;
  {
    float d0 = 0.f, d1 = 0.f;
#pragma unroll 1
    for (int i = 0; i < 16; i += 2) {
      float4 q0 = qr[i],     k0 = kct[i * 64 + lane];
      float4 q1 = qr[i + 1], k1 = kct[(i + 1) * 64 + lane];
      d0 += q0.x * k0.x + q0.z * k0.z;
      d1 += q0.y * k0.y + q0.w * k0.w;
      d0 += q1.x * k1.x + q1.z * k1.z;
      d1 += q1.y * k1.y + q1.w * k1.w;
    }
    sc = (d0 + d1) * scale;
  }

  float comp_out = 0.f;
  if (nv > 0) {
    float scomp = (lane < nv) ? sc : NEGBIG;
    float m = fmaxf(wave_max(scomp), snk);
    float e = (lane < nv) ? expf(sc - m) : 0.f;
    float S = wave_sum(e) + expf(snk - m);
    float pn = e / S;
    const float* vcp = vc + lane;
    float c0 = 0.f, c1 = 0.f, c2 = 0.f, c3 = 0.f;
    pv16<0>(vcp, pn, c0, c1, c2, c3);
    pv16<16>(vcp + 1024, pn, c0, c1, c2, c3);
    pv16<32>(vcp + 2048, pn, c0, c1, c2, c3);
    pv16<48>(vcp + 3072, pn, c0, c1, c2, c3);
    comp_out = (c0 + c1) + (c2 + c3);
  }

  {
    float selv = (lane < nv) ? sc : -FLT_MAX;
#pragma unroll
    for (int it = 0; it < 16; ++it) {
      float bv = selv; int bi = lane;
#pragma unroll
      for (int off = 32; off; off >>= 1) {
        float ov = __shfl_xor(bv, off, 64);
        int oi = __shfl_xor(bi, off, 64);
        if (ov > bv || (ov == bv && oi < bi)) { bv = ov; bi = oi; }
      }
      if (lane == 0) shsel[wid][it] = bi;
      if (lane == bi) selv = -INFINITY;
    }
  }

  float M = NEGBIG, S = 0.f, osel = 0.f;
#pragma unroll 1
  for (int c = 0; c < 8; ++c) {
    int b0 = shsel[wid][2 * c], b1 = shsel[wid][2 * c + 1];
    int base0 = b0 * 32, base1 = b1 * 32;
    if (base0 > qpos && base1 > qpos) continue;
    int myb = (lane < 32) ? b0 : b1;
    int tok = myb * 32 + (lane & 31);
    bool ok = (tok <= qpos);
    const float4* kp = ks4 + myb * 512 + (lane & 31);
    float s = ok ? qk_dot(qr, kp) * scale : NEGBIG;
    float Mn = fmaxf(M, wave_max(s));
    float e = ok ? expf(s - Mn) : 0.f;
    float cs = wave_sum(e);
    float corr = expf(M - Mn);
    S = S * corr + cs;
    const float* v0 = vbuf + base0 * 64 + lane;
    const float* v1 = vbuf + base1 * 64 + lane;
    float a0 = 0.f, a1 = 0.f, a2 = 0.f, a3 = 0.f;
    pv16<0>(v0, e, a0, a1, a2, a3);
    pv16<16>(v0 + 1024, e, a0, a1, a2, a3);
    pv16<32>(v1, e, a0, a1, a2, a3);
    pv16<48>(v1 + 1024, e, a0, a1, a2, a3);
    osel = osel * corr + ((a0 + a1) + (a2 + a3));
    M = Mn;
  }
  osel /= S;

  // ======== PHASE 2: window with cooperative LDS staging ========
  float Mw = NEGBIG, Sw = 0.f, osw = 0.f;
  int kstart = qpos - 511; if (kstart < 0) kstart = 0;
  int sbf = kstart >> 5, sbl = qpos >> 5;
  const float4* vbuf4 = reinterpret_cast<const float4*>(vbuf);
#pragma unroll 1
  for (int sb = sbf; sb <= sbl; sb += 2) {
    int sb1 = sb + 1;
    bool v1ok = (sb1 <= sbl);
    int sb1c = v1ok ? sb1 : sb;
    __syncthreads();
#pragma unroll
    for (int j = 0; j < 2; ++j) {
      int g = j * 512 + tid;
      int blk = (g >> 9) ? sb1c : sb;
      stgK[g] = ks4[blk * 512 + (g & 511)];
    }
#pragma unroll
    for (int j = 0; j < 2; ++j) {
      int g = j * 512 + tid;
      int row = g >> 4;
      int srow = (row < 32) ? (sb * 32 + row) : (sb1c * 32 + (row - 32));
      reinterpret_cast<float4*>(stgV)[g] = vbuf4[srow * 16 + (g & 15)];
    }
    __syncthreads();
    int myoff = (lane < 32) ? 0 : 512;
    int tok = ((lane < 32) ? sb : sb1c) * 32 + (lane & 31);
    bool ok = (tok >= kstart) && (tok <= qpos) && ((lane < 32) || v1ok);
    const float4* kp = stgK + myoff + (lane & 31);
    float s = ok ? qk_dot(qr, kp) * scale : NEGBIG;
    float Mn = fmaxf(Mw, wave_max(s));
    float e = ok ? expf(s - Mn) : 0.f;
    float cs = wave_sum(e);
    float corr = expf(Mw - Mn);
    Sw = Sw * corr + cs;
    const float* v0 = stgV + lane;
    const float* v1 = stgV + 2048 + lane;
    float a0 = 0.f, a1 = 0.f, a2 = 0.f, a3 = 0.f;
    pv16<0>(v0, e, a0, a1, a2, a3);
    pv16<16>(v0 + 1024, e, a0, a1, a2, a3);
    pv16<32>(v1, e, a0, a1, a2, a3);
    pv16<48>(v1 + 1024, e, a0, a1, a2, a3);
    osw = osw * corr + ((a0 + a1) + (a2 + a3));
    Mw = Mn;
  }
  {
    float Mf = fmaxf(Mw, snk);
    float corr = expf(Mw - Mf);
    float Sf = Sw * corr + expf(snk - Mf);
    osw = osw * corr / Sf;
  }

  mixed[r * 64 + lane] = ga0 * comp_out + ga1 * osel + ga2 * osw;
}

// ---------------- launch ----------------
extern "C" void kernel_launch(void* const* d_in, const int* in_sizes, int n_in,
                              void* d_out, int out_size, void* d_ws, size_t ws_size,
                              hipStream_t stream) {
  const float* h      = (const float*)d_in[0];
  const float* w_qc   = (const float*)d_in[1];
  const float* w_qup  = (const float*)d_in[2];
  const float* w_k    = (const float*)d_in[3];
  const float* w_v    = (const float*)d_in[4];
  const float* g_qn   = (const float*)d_in[5];
  const float* g_kn   = (const float*)d_in[6];
  const float* w_gate = (const float*)d_in[7];
  const float* b_gate = (const float*)d_in[8];
  const float* sink   = (const float*)d_in[9];
  const float* wog    = (const float*)d_in[10];
  const float* w_out  = (const float*)d_in[11];
  float* out = (float*)d_out;

  float* ws = (float*)d_ws;
  float* hc  = ws;                    // 2048*256 (dead after qup -> reused as wT)
  float* qb  = hc + 2048 * 256;       // 2048*512
  float* kb  = qb + 2048 * 512;       // 2048*64
  float* vb  = kb + 2048 * 64;        // 2048*64
  float* vc  = vb + 2048 * 64;        // 64*64
  float* mx  = vc + 64 * 64;          // 2048*512
  float* y1  = mx + 2048 * 512;       // 2048*1024 f32 slot (reused as bf16 y1b)
  float* kS  = y1 + 2048 * 1024;      // 2048*64 block-local K
  float* kct4 = kS + 2048 * 64;       // 16*64*4
  float* ct  = kct4 + 16 * 64 * 4;    // 2048*16 rope cos
  float* st  = ct + 2048 * 16;        // 2048*16 rope sin

  unsigned short* y1b = (unsigned short*)y1;   // 2048*1024 bf16 (4MB of 8MB slot)
  unsigned short* wT  = (unsigned short*)hc;   // 1024*1024 bf16 (2MB slot, hc dead)

  dim3 blk(256);
  rope_table_kernel<<<dim3(128), blk, 0, stream>>>(ct, st);
  gemm_qckv<<<dim3(6, 32), blk, 0, stream>>>(h, w_qc, w_k, w_v, hc, kb, vb);
  gemm_tile<<<dim3(8, 32), blk, 0, stream>>>(hc, w_qup, qb, 2048, 512, 256, 256, 512, 512);
  // hc now dead -> transpose+convert w_out into its slot
  wtrans_kernel<<<dim3(4096), blk, 0, stream>>>(w_out, wT);
  rope_rms_fused<<<dim3(4608), blk, 0, stream>>>(qb, kb, g_qn, g_kn, kS, ct, st);
  compress_kernel<<<dim3(64), dim3(64), 0, stream>>>(kb, vb, kct4, vc);
  attn_kernel<<<dim3(2048), dim3(512), 0, stream>>>(qb, kS, vb, kct4, vc, w_gate, b_gate, sink, mx);
  // grouped projection -> bf16 y1b
  gemm_dual_b16<<<dim3(16, 32), blk, 0, stream>>>(mx, mx + 256, wog, wog + 256 * 512,
                                                  y1b, y1b + 512, 256, 512, 512, 1024, 8);
  // out = y1b @ wT^T via MFMA bf16
  gemm_out_mfma<<<dim3(16, 32), blk, 0, stream>>>(y1b, wT, out);
}

// Round 25
// 390.017 us; speedup vs baseline: 1.2797x; 1.0243x over previous
//
#include <hip/hip_runtime.h>
#include <hip/hip_bf16.h>
#include <float.h>
#include <math.h>

typedef __hip_bfloat16 bf16;
typedef float v2f __attribute__((ext_vector_type(2)));
typedef float f32x4 __attribute__((ext_vector_type(4)));
typedef short bf16x8 __attribute__((ext_vector_type(8)));

#define NEGBIG (-1e30f)

__device__ __forceinline__ float ldv(const float* p, int i) { return p[i]; }

// RNE f32 -> bf16 (bit pattern), matches HW rounding.
__device__ __forceinline__ unsigned short f2bf(float x) {
  unsigned u = __float_as_uint(x);
  u += 0x7FFFu + ((u >> 16) & 1u);
  return (unsigned short)(u >> 16);
}

__device__ __forceinline__ float wave_sum(float v) {
#pragma unroll
  for (int off = 32; off; off >>= 1) v += __shfl_xor(v, off, 64);
  return v;
}
__device__ __forceinline__ float wave_max(float v) {
#pragma unroll
  for (int off = 32; off; off >>= 1) v = fmaxf(v, __shfl_xor(v, off, 64));
  return v;
}

__device__ __forceinline__ float rdlane(float v, int l) {
  return __uint_as_float(__builtin_amdgcn_readlane(__float_as_uint(v), l));
}

// PV over 16 tokens (readlane broadcast, imm-offset V rows). 4 chains.
template <int L0>
__device__ __forceinline__ void pv16(const float* __restrict__ vp, float e,
                                     float& a0, float& a1, float& a2, float& a3) {
#pragma unroll
  for (int t = 0; t < 16; t += 4) {
    float p0 = rdlane(e, L0 + t + 0);
    float p1 = rdlane(e, L0 + t + 1);
    float p2 = rdlane(e, L0 + t + 2);
    float p3 = rdlane(e, L0 + t + 3);
    a0 += p0 * vp[(t + 0) * 64];
    a1 += p1 * vp[(t + 1) * 64];
    a2 += p2 * vp[(t + 2) * 64];
    a3 += p3 * vp[(t + 3) * 64];
  }
}

// QK dot against one 32-token K block slice, packed (v_pk_fma_f32).
__device__ __forceinline__ float qk_dot(const float4* __restrict__ qr,
                                        const float4* __restrict__ kp) {
  v2f d01 = {0.f, 0.f}, d23 = {0.f, 0.f};
#pragma unroll 1
  for (int i = 0; i < 16; i += 2) {
    float4 q0 = qr[i],     k0 = kp[i * 32];
    float4 q1 = qr[i + 1], k1 = kp[i * 32 + 32];
    d01 += (v2f){q0.x, q0.y} * (v2f){k0.x, k0.y};
    d23 += (v2f){q0.z, q0.w} * (v2f){k0.z, k0.w};
    d01 += (v2f){q1.x, q1.y} * (v2f){k1.x, k1.y};
    d23 += (v2f){q1.z, q1.w} * (v2f){k1.z, k1.w};
  }
  v2f d = d01 + d23;
  return d.x + d.y;
}

// ---------------- pipelined f32 GEMM core (measured-best 4x4/256t) ----------
__device__ __forceinline__ void gemm_core(
    const float* __restrict__ A, const float* __restrict__ B, float* __restrict__ C,
    int K, int lda, int ldb, int ldc, int row0, int col0)
{
  __shared__ __align__(16) float As[2][16][68];
  __shared__ __align__(16) float Bs[2][16][68];
  const int tid = threadIdx.x;
  const int tx = tid & 15, ty = tid >> 4;
  const int ar = tid >> 2;
  const int ak = (tid & 3) * 4;
  const int bk = tid >> 4;
  const int bc = (tid & 15) * 4;

  const int nk = K >> 4;
  float4 a4 = *reinterpret_cast<const float4*>(&A[(row0 + ar) * lda + ak]);
  float4 b4 = *reinterpret_cast<const float4*>(&B[bk * ldb + col0 + bc]);
  {
    As[0][ak + 0][ar] = a4.x; As[0][ak + 1][ar] = a4.y;
    As[0][ak + 2][ar] = a4.z; As[0][ak + 3][ar] = a4.w;
    *reinterpret_cast<float4*>(&Bs[0][bk][bc]) = b4;
  }

  v2f acc01[4] = {};
  v2f acc23[4] = {};
  for (int t = 0; t < nk; ++t) {
    const int cur = t & 1;
    if (t + 1 < nk) {
      int k0 = (t + 1) * 16;
      a4 = *reinterpret_cast<const float4*>(&A[(row0 + ar) * lda + k0 + ak]);
      b4 = *reinterpret_cast<const float4*>(&B[(k0 + bk) * ldb + col0 + bc]);
    }
    __syncthreads();
#pragma unroll
    for (int kk = 0; kk < 16; ++kk) {
      float4 av = *reinterpret_cast<const float4*>(&As[cur][kk][ty * 4]);
      float4 bv = *reinterpret_cast<const float4*>(&Bs[cur][kk][tx * 4]);
      v2f b01; b01.x = bv.x; b01.y = bv.y;
      v2f b23; b23.x = bv.z; b23.y = bv.w;
      float a[4] = {av.x, av.y, av.z, av.w};
#pragma unroll
      for (int i = 0; i < 4; ++i) {
        v2f as; as.x = a[i]; as.y = a[i];
        acc01[i] += as * b01;
        acc23[i] += as * b23;
      }
    }
    if (t + 1 < nk) {
      const int nxt = cur ^ 1;
      As[nxt][ak + 0][ar] = a4.x; As[nxt][ak + 1][ar] = a4.y;
      As[nxt][ak + 2][ar] = a4.z; As[nxt][ak + 3][ar] = a4.w;
      *reinterpret_cast<float4*>(&Bs[nxt][bk][bc]) = b4;
    }
  }
#pragma unroll
  for (int i = 0; i < 4; ++i) {
    float4 o = make_float4(acc01[i].x, acc01[i].y, acc23[i].x, acc23[i].y);
    *reinterpret_cast<float4*>(&C[(row0 + ty * 4 + i) * ldc + col0 + tx * 4]) = o;
  }
}

__global__ __launch_bounds__(256) void gemm_tile(
    const float* __restrict__ A, const float* __restrict__ B, float* __restrict__ C,
    int M, int N, int K, int lda, int ldb, int ldc)
{
  gemm_core(A, B, C, K, lda, ldb, ldc, blockIdx.y * 64, blockIdx.x * 64);
}

// Fused h-projections: hc (x<4), kb (x==4), vb (x==5). One dispatch, 192 blocks.
__global__ __launch_bounds__(256) void gemm_qckv(
    const float* __restrict__ h, const float* __restrict__ w_qc,
    const float* __restrict__ w_k, const float* __restrict__ w_v,
    float* __restrict__ hc, float* __restrict__ kb, float* __restrict__ vb)
{
  const int x = blockIdx.x;
  if (x < 4) {
    gemm_core(h, w_qc, hc, 1024, 1024, 256, 256, blockIdx.y * 64, x * 64);
  } else if (x == 4) {
    gemm_core(h, w_k, kb, 1024, 1024, 64, 64, blockIdx.y * 64, 0);
  } else {
    gemm_core(h, w_v, vb, 1024, 1024, 64, 64, blockIdx.y * 64, 0);
  }
}

// Transpose+convert w_out (1024x1024 f32, row-major [k][col]) -> wT bf16 [col][k].
__global__ __launch_bounds__(256) void wtrans_kernel(
    const float* __restrict__ w, unsigned short* __restrict__ wT)
{
  int gid = blockIdx.x * 256 + threadIdx.x;   // 1M threads
  int k = gid >> 10, col = gid & 1023;
  wT[col * 1024 + k] = f2bf(w[k * 1024 + col]);
}

// Transpose+convert w_out_group (2x256x512 f32 [g][f][i]) -> wogT bf16 [g][i][f].
__global__ __launch_bounds__(256) void wogtrans_kernel(
    const float* __restrict__ wog, unsigned short* __restrict__ wogT)
{
  int gid = blockIdx.x * 256 + threadIdx.x;   // 262144 threads
  int g = gid >> 17;
  int rem = gid & 131071;
  int i = rem >> 8;     // col 0..511
  int f = rem & 255;    // k   0..255
  wogT[(g * 512 + i) * 256 + f] = f2bf(wog[g * 131072 + f * 512 + i]);
}

// ---------------- MFMA bf16 group projection: y1b = mxb @ wogT^T ------------
// Per group g: y1b[t][g*512+c] = sum_f mxb[t][g*256+f] * wogT[g][c][f], K=256.
// Same fragment layouts as gemm_out_mfma (r24, HW-validated).
__global__ __launch_bounds__(256) void gemm_group_mfma(
    const unsigned short* __restrict__ mxb, const unsigned short* __restrict__ wogT,
    unsigned short* __restrict__ y1b)
{
  const int lane = threadIdx.x & 63;
  const int wid = threadIdx.x >> 6;
  const int g = blockIdx.x >> 3;               // group 0..1
  const int colbase = (blockIdx.x & 7) * 64;   // within group's 512
  const int rowbase = blockIdx.y * 64 + wid * 16;
  const int rc = lane & 15;
  const int kg = lane >> 4;
  const unsigned short* ap = mxb + (rowbase + rc) * 512 + g * 256 + kg * 8;
  const unsigned short* bp = wogT + (g * 512 + colbase + rc) * 256 + kg * 8;

  f32x4 acc0 = {0.f, 0.f, 0.f, 0.f};
  f32x4 acc1 = {0.f, 0.f, 0.f, 0.f};
  f32x4 acc2 = {0.f, 0.f, 0.f, 0.f};
  f32x4 acc3 = {0.f, 0.f, 0.f, 0.f};
#pragma unroll
  for (int k0 = 0; k0 < 256; k0 += 32) {
    bf16x8 a = *reinterpret_cast<const bf16x8*>(ap + k0);
    bf16x8 b0 = *reinterpret_cast<const bf16x8*>(bp + k0);
    bf16x8 b1 = *reinterpret_cast<const bf16x8*>(bp + 16 * 256 + k0);
    bf16x8 b2 = *reinterpret_cast<const bf16x8*>(bp + 32 * 256 + k0);
    bf16x8 b3 = *reinterpret_cast<const bf16x8*>(bp + 48 * 256 + k0);
    acc0 = __builtin_amdgcn_mfma_f32_16x16x32_bf16(a, b0, acc0, 0, 0, 0);
    acc1 = __builtin_amdgcn_mfma_f32_16x16x32_bf16(a, b1, acc1, 0, 0, 0);
    acc2 = __builtin_amdgcn_mfma_f32_16x16x32_bf16(a, b2, acc2, 0, 0, 0);
    acc3 = __builtin_amdgcn_mfma_f32_16x16x32_bf16(a, b3, acc3, 0, 0, 0);
  }
#pragma unroll
  for (int j = 0; j < 4; ++j) {
    int row = rowbase + kg * 4 + j;
    unsigned short* yp = y1b + row * 1024 + g * 512 + colbase;
    yp[rc]      = f2bf(acc0[j]);
    yp[16 + rc] = f2bf(acc1[j]);
    yp[32 + rc] = f2bf(acc2[j]);
    yp[48 + rc] = f2bf(acc3[j]);
  }
}

// ---------------- MFMA bf16 out-GEMM: out[2048x1024] = y1b @ wT^T (r24) -----
__global__ __launch_bounds__(256) void gemm_out_mfma(
    const unsigned short* __restrict__ y1b, const unsigned short* __restrict__ wT,
    float* __restrict__ out)
{
  const int lane = threadIdx.x & 63;
  const int wid = threadIdx.x >> 6;
  const int rowbase = blockIdx.y * 64 + wid * 16;
  const int colbase = blockIdx.x * 64;
  const int rc = lane & 15;
  const int kg = lane >> 4;
  const unsigned short* ap = y1b + (rowbase + rc) * 1024 + kg * 8;
  const unsigned short* bp = wT + (colbase + rc) * 1024 + kg * 8;

  f32x4 acc0 = {0.f, 0.f, 0.f, 0.f};
  f32x4 acc1 = {0.f, 0.f, 0.f, 0.f};
  f32x4 acc2 = {0.f, 0.f, 0.f, 0.f};
  f32x4 acc3 = {0.f, 0.f, 0.f, 0.f};
#pragma unroll 2
  for (int k0 = 0; k0 < 1024; k0 += 32) {
    bf16x8 a = *reinterpret_cast<const bf16x8*>(ap + k0);
    bf16x8 b0 = *reinterpret_cast<const bf16x8*>(bp + k0);
    bf16x8 b1 = *reinterpret_cast<const bf16x8*>(bp + 16 * 1024 + k0);
    bf16x8 b2 = *reinterpret_cast<const bf16x8*>(bp + 32 * 1024 + k0);
    bf16x8 b3 = *reinterpret_cast<const bf16x8*>(bp + 48 * 1024 + k0);
    acc0 = __builtin_amdgcn_mfma_f32_16x16x32_bf16(a, b0, acc0, 0, 0, 0);
    acc1 = __builtin_amdgcn_mfma_f32_16x16x32_bf16(a, b1, acc1, 0, 0, 0);
    acc2 = __builtin_amdgcn_mfma_f32_16x16x32_bf16(a, b2, acc2, 0, 0, 0);
    acc3 = __builtin_amdgcn_mfma_f32_16x16x32_bf16(a, b3, acc3, 0, 0, 0);
  }
#pragma unroll
  for (int j = 0; j < 4; ++j) {
    int row = rowbase + kg * 4 + j;
    out[row * 1024 + colbase + rc]      = acc0[j];
    out[row * 1024 + colbase + 16 + rc] = acc1[j];
    out[row * 1024 + colbase + 32 + rc] = acc2[j];
    out[row * 1024 + colbase + 48 + rc] = acc3[j];
  }
}

// ---------------- RoPE cos/sin table (double trig once, f32 store) ----------
__global__ __launch_bounds__(256) void rope_table_kernel(float* __restrict__ ct,
                                                         float* __restrict__ st) {
  int tid = blockIdx.x * 256 + threadIdx.x;
  if (tid >= 2048 * 16) return;
  int pos = tid >> 4, i = tid & 15;
  double ang = (double)pos * pow(10000.0, -(double)i / 16.0);
  ct[tid] = (float)cos(ang);
  st[tid] = (float)sin(ang);
}

// ---------------- RoPE (first 32 dims) + RMSNorm (fused q+k) ----------------
__device__ __forceinline__ void rope_body(
    float* __restrict__ x, const float* __restrict__ g, int rows, int posShift,
    float* __restrict__ kS, const float* __restrict__ ct, const float* __restrict__ st,
    int bx)
{
  const int lane = threadIdx.x & 63;
  const int wid = threadIdx.x >> 6;
  const int r = bx * 4 + wid;
  if (r >= rows) return;
  const int pos = r >> posShift;
  float val = x[r * 64 + lane];
  float p = __shfl_xor(val, 16, 64);
  float out = val;
  if (lane < 32) {
    int i = lane & 15;
    float cc = ct[pos * 16 + i], ss = st[pos * 16 + i];
    out = (lane < 16) ? (val * cc - p * ss) : (p * ss + val * cc);
  }
  float ms = wave_sum(out * out) * (1.0f / 64.0f);
  float rn = rsqrtf(ms + 1e-6f);
  float res = out * rn * ldv(g, lane);
  x[r * 64 + lane] = res;
  if (kS) {
    int f4 = (r >> 5) * 512 + (lane >> 2) * 32 + (r & 31);
    kS[f4 * 4 + (lane & 3)] = res;
  }
}

__global__ __launch_bounds__(256) void rope_rms_fused(
    float* __restrict__ qx, float* __restrict__ kx,
    const float* __restrict__ gq, const float* __restrict__ gk,
    float* __restrict__ kS, const float* __restrict__ ct, const float* __restrict__ st)
{
  const int bx = blockIdx.x;
  if (bx < 4096) rope_body(qx, gq, 16384, 3, nullptr, ct, st, bx);
  else           rope_body(kx, gk, 2048, 0, kS, ct, st, bx - 4096);
}

// ---------------- block-mean compression: kcT4 (d4-major) + vc --------------
__global__ void compress_kernel(const float* __restrict__ k, const float* __restrict__ v,
                                float* __restrict__ kcT4, float* __restrict__ vc)
{
  const int n = blockIdx.x;
  const int d = threadIdx.x;
  float sk = 0.f, sv = 0.f;
  for (int j = 0; j < 32; ++j) {
    sk += k[(n * 32 + j) * 64 + d];
    sv += v[(n * 32 + j) * 64 + d];
  }
  kcT4[(d >> 2) * 256 + n * 4 + (d & 3)] = sk * (1.0f / 32.0f);
  vc[n * 64 + d] = sv * (1.0f / 32.0f);
}

// ---------------- attention: 8 waves (= 8 heads) per qpos block (r23) -------
// Output stored as bf16 (feeds MFMA group projection). Scores/top-k untouched.
__global__ __launch_bounds__(512) void attn_kernel(
    const float* __restrict__ q, const float* __restrict__ kS, const float* __restrict__ vbuf,
    const float* __restrict__ kcT4, const float* __restrict__ vc,
    const float* __restrict__ w_gate, const float* __restrict__ b_gate,
    const float* __restrict__ sink, unsigned short* __restrict__ mixed)
{
  __shared__ __align__(16) float4 stgK[1024];
  __shared__ __align__(16) float stgV[4096];
  __shared__ __align__(16) float shq[8][64];
  __shared__ int shsel[8][16];
  const int tid = threadIdx.x;
  const int lane = tid & 63;
  const int wid = tid >> 6;
  const int qpos = 2047 - blockIdx.x;
  const int h = wid;
  const int r = qpos * 8 + h;
  const float scale = 0.125f;

  float qv = q[r * 64 + lane];
  shq[wid][lane] = qv;

  // ---- gate ----
  float z0 = qv * ldv(w_gate, lane * 3 + 0);
  float z1 = qv * ldv(w_gate, lane * 3 + 1);
  float z2 = qv * ldv(w_gate, lane * 3 + 2);
  z0 = wave_sum(z0) + ldv(b_gate, 0);
  z1 = wave_sum(z1) + ldv(b_gate, 1);
  z2 = wave_sum(z2) + ldv(b_gate, 2);
  float ga0 = 1.f / (1.f + expf(-z0));
  float ga1 = 1.f / (1.f + expf(-z1));
  float ga2 = 1.f / (1.f + expf(-z2));
  float gs = fmaxf(ga0 + ga1 + ga2, 1e-6f);
  float ginv = 1.f / gs;
  ga0 *= ginv; ga1 *= ginv; ga2 *= ginv;

  const float4* qr = reinterpret_cast<const float4*>(&shq[wid][0]);
  const float4* ks4 = reinterpret_cast<const float4*>(kS);
  const float4* kct = reinterpret_cast<const float4*>(kcT4);
  const float snk = ldv(sink, h);
  const int nv = (qpos + 1) >> 5;

  // ======== PHASE 1: per-wave: comp + top-k + selected ========
  float sc;
  {
    float d0 = 0.f, d1 = 0.f;
#pragma unroll 1
    for (int i = 0; i < 16; i += 2) {
      float4 q0 = qr[i],     k0 = kct[i * 64 + lane];
      float4 q1 = qr[i + 1], k1 = kct[(i + 1) * 64 + lane];
      d0 += q0.x * k0.x + q0.z * k0.z;
      d1 += q0.y * k0.y + q0.w * k0.w;
      d0 += q1.x * k1.x + q1.z * k1.z;
      d1 += q1.y * k1.y + q1.w * k1.w;
    }
    sc = (d0 + d1) * scale;
  }

  float comp_out = 0.f;
  if (nv > 0) {
    float scomp = (lane < nv) ? sc : NEGBIG;
    float m = fmaxf(wave_max(scomp), snk);
    float e = (lane < nv) ? expf(sc - m) : 0.f;
    float S = wave_sum(e) + expf(snk - m);
    float pn = e / S;
    const float* vcp = vc + lane;
    float c0 = 0.f, c1 = 0.f, c2 = 0.f, c3 = 0.f;
    pv16<0>(vcp, pn, c0, c1, c2, c3);
    pv16<16>(vcp + 1024, pn, c0, c1, c2, c3);
    pv16<32>(vcp + 2048, pn, c0, c1, c2, c3);
    pv16<48>(vcp + 3072, pn, c0, c1, c2, c3);
    comp_out = (c0 + c1) + (c2 + c3);
  }

  {
    float selv = (lane < nv) ? sc : -FLT_MAX;
#pragma unroll
    for (int it = 0; it < 16; ++it) {
      float bv = selv; int bi = lane;
#pragma unroll
      for (int off = 32; off; off >>= 1) {
        float ov = __shfl_xor(bv, off, 64);
        int oi = __shfl_xor(bi, off, 64);
        if (ov > bv || (ov == bv && oi < bi)) { bv = ov; bi = oi; }
      }
      if (lane == 0) shsel[wid][it] = bi;
      if (lane == bi) selv = -INFINITY;
    }
  }

  float M = NEGBIG, S = 0.f, osel = 0.f;
#pragma unroll 1
  for (int c = 0; c < 8; ++c) {
    int b0 = shsel[wid][2 * c], b1 = shsel[wid][2 * c + 1];
    int base0 = b0 * 32, base1 = b1 * 32;
    if (base0 > qpos && base1 > qpos) continue;
    int myb = (lane < 32) ? b0 : b1;
    int tok = myb * 32 + (lane & 31);
    bool ok = (tok <= qpos);
    const float4* kp = ks4 + myb * 512 + (lane & 31);
    float s = ok ? qk_dot(qr, kp) * scale : NEGBIG;
    float Mn = fmaxf(M, wave_max(s));
    float e = ok ? expf(s - Mn) : 0.f;
    float cs = wave_sum(e);
    float corr = expf(M - Mn);
    S = S * corr + cs;
    const float* v0 = vbuf + base0 * 64 + lane;
    const float* v1 = vbuf + base1 * 64 + lane;
    float a0 = 0.f, a1 = 0.f, a2 = 0.f, a3 = 0.f;
    pv16<0>(v0, e, a0, a1, a2, a3);
    pv16<16>(v0 + 1024, e, a0, a1, a2, a3);
    pv16<32>(v1, e, a0, a1, a2, a3);
    pv16<48>(v1 + 1024, e, a0, a1, a2, a3);
    osel = osel * corr + ((a0 + a1) + (a2 + a3));
    M = Mn;
  }
  osel /= S;

  // ======== PHASE 2: window with cooperative LDS staging ========
  float Mw = NEGBIG, Sw = 0.f, osw = 0.f;
  int kstart = qpos - 511; if (kstart < 0) kstart = 0;
  int sbf = kstart >> 5, sbl = qpos >> 5;
  const float4* vbuf4 = reinterpret_cast<const float4*>(vbuf);
#pragma unroll 1
  for (int sb = sbf; sb <= sbl; sb += 2) {
    int sb1 = sb + 1;
    bool v1ok = (sb1 <= sbl);
    int sb1c = v1ok ? sb1 : sb;
    __syncthreads();
#pragma unroll
    for (int j = 0; j < 2; ++j) {
      int g = j * 512 + tid;
      int blk = (g >> 9) ? sb1c : sb;
      stgK[g] = ks4[blk * 512 + (g & 511)];
    }
#pragma unroll
    for (int j = 0; j < 2; ++j) {
      int g = j * 512 + tid;
      int row = g >> 4;
      int srow = (row < 32) ? (sb * 32 + row) : (sb1c * 32 + (row - 32));
      reinterpret_cast<float4*>(stgV)[g] = vbuf4[srow * 16 + (g & 15)];
    }
    __syncthreads();
    int myoff = (lane < 32) ? 0 : 512;
    int tok = ((lane < 32) ? sb : sb1c) * 32 + (lane & 31);
    bool ok = (tok >= kstart) && (tok <= qpos) && ((lane < 32) || v1ok);
    const float4* kp = stgK + myoff + (lane & 31);
    float s = ok ? qk_dot(qr, kp) * scale : NEGBIG;
    float Mn = fmaxf(Mw, wave_max(s));
    float e = ok ? expf(s - Mn) : 0.f;
    float cs = wave_sum(e);
    float corr = expf(Mw - Mn);
    Sw = Sw * corr + cs;
    const float* v0 = stgV + lane;
    const float* v1 = stgV + 2048 + lane;
    float a0 = 0.f, a1 = 0.f, a2 = 0.f, a3 = 0.f;
    pv16<0>(v0, e, a0, a1, a2, a3);
    pv16<16>(v0 + 1024, e, a0, a1, a2, a3);
    pv16<32>(v1, e, a0, a1, a2, a3);
    pv16<48>(v1 + 1024, e, a0, a1, a2, a3);
    osw = osw * corr + ((a0 + a1) + (a2 + a3));
    Mw = Mn;
  }
  {
    float Mf = fmaxf(Mw, snk);
    float corr = expf(Mw - Mf);
    float Sf = Sw * corr + expf(snk - Mf);
    osw = osw * corr / Sf;
  }

  mixed[r * 64 + lane] = f2bf(ga0 * comp_out + ga1 * osel + ga2 * osw);
}

// ---------------- launch ----------------
extern "C" void kernel_launch(void* const* d_in, const int* in_sizes, int n_in,
                              void* d_out, int out_size, void* d_ws, size_t ws_size,
                              hipStream_t stream) {
  const float* h      = (const float*)d_in[0];
  const float* w_qc   = (const float*)d_in[1];
  const float* w_qup  = (const float*)d_in[2];
  const float* w_k    = (const float*)d_in[3];
  const float* w_v    = (const float*)d_in[4];
  const float* g_qn   = (const float*)d_in[5];
  const float* g_kn   = (const float*)d_in[6];
  const float* w_gate = (const float*)d_in[7];
  const float* b_gate = (const float*)d_in[8];
  const float* sink   = (const float*)d_in[9];
  const float* wog    = (const float*)d_in[10];
  const float* w_out  = (const float*)d_in[11];
  float* out = (float*)d_out;

  float* ws = (float*)d_ws;
  float* hc  = ws;                    // 2048*256 (dead after qup -> reused as wT)
  float* qb  = hc + 2048 * 256;       // 2048*512
  float* kb  = qb + 2048 * 512;       // 2048*64
  float* vb  = kb + 2048 * 64;        // 2048*64
  float* vc  = vb + 2048 * 64;        // 64*64
  float* mx  = vc + 64 * 64;          // 2048*512 slot (bf16 mixed uses half)
  float* y1  = mx + 2048 * 512;       // 2048*1024 f32 slot (bf16 y1b + wogT)
  float* kS  = y1 + 2048 * 1024;      // 2048*64 block-local K
  float* kct4 = kS + 2048 * 64;       // 16*64*4
  float* ct  = kct4 + 16 * 64 * 4;    // 2048*16 rope cos
  float* st  = ct + 2048 * 16;        // 2048*16 rope sin

  unsigned short* mxb  = (unsigned short*)mx;             // 2048*512 bf16
  unsigned short* y1b  = (unsigned short*)y1;             // 2048*1024 bf16 (first 4MB)
  unsigned short* wogT = (unsigned short*)(y1 + 1048576); // 2*512*256 bf16 (second half)
  unsigned short* wT   = (unsigned short*)hc;             // 1024*1024 bf16

  dim3 blk(256);
  rope_table_kernel<<<dim3(128), blk, 0, stream>>>(ct, st);
  gemm_qckv<<<dim3(6, 32), blk, 0, stream>>>(h, w_qc, w_k, w_v, hc, kb, vb);
  gemm_tile<<<dim3(8, 32), blk, 0, stream>>>(hc, w_qup, qb, 2048, 512, 256, 256, 512, 512);
  // hc now dead -> transpose+convert w_out into its slot; wogT into y1 2nd half
  wtrans_kernel<<<dim3(4096), blk, 0, stream>>>(w_out, wT);
  wogtrans_kernel<<<dim3(1024), blk, 0, stream>>>(wog, wogT);
  rope_rms_fused<<<dim3(4608), blk, 0, stream>>>(qb, kb, g_qn, g_kn, kS, ct, st);
  compress_kernel<<<dim3(64), dim3(64), 0, stream>>>(kb, vb, kct4, vc);
  attn_kernel<<<dim3(2048), dim3(512), 0, stream>>>(qb, kS, vb, kct4, vc, w_gate, b_gate, sink, mxb);
  // group projection via MFMA: y1b = mxb @ wogT^T
  gemm_group_mfma<<<dim3(16, 32), blk, 0, stream>>>(mxb, wogT, y1b);
  // out = y1b @ wT^T via MFMA bf16
  gemm_out_mfma<<<dim3(16, 32), blk, 0, stream>>>(y1b, wT, out);
}

// Round 26
// 384.318 us; speedup vs baseline: 1.2987x; 1.0148x over previous
//
#include <hip/hip_runtime.h>
#include <hip/hip_bf16.h>
#include <float.h>
#include <math.h>

typedef __hip_bfloat16 bf16;
typedef float v2f __attribute__((ext_vector_type(2)));
typedef float f32x4 __attribute__((ext_vector_type(4)));
typedef short bf16x8 __attribute__((ext_vector_type(8)));

#define NEGBIG (-1e30f)

__device__ __forceinline__ float ldv(const float* p, int i) { return p[i]; }

// RNE f32 -> bf16 (bit pattern), matches HW rounding.
__device__ __forceinline__ unsigned short f2bf(float x) {
  unsigned u = __float_as_uint(x);
  u += 0x7FFFu + ((u >> 16) & 1u);
  return (unsigned short)(u >> 16);
}

__device__ __forceinline__ float wave_sum(float v) {
#pragma unroll
  for (int off = 32; off; off >>= 1) v += __shfl_xor(v, off, 64);
  return v;
}
__device__ __forceinline__ float wave_max(float v) {
#pragma unroll
  for (int off = 32; off; off >>= 1) v = fmaxf(v, __shfl_xor(v, off, 64));
  return v;
}

__device__ __forceinline__ float rdlane(float v, int l) {
  return __uint_as_float(__builtin_amdgcn_readlane(__float_as_uint(v), l));
}

// PV over 16 tokens, f32 V (used for comp branch only). 4 chains.
template <int L0>
__device__ __forceinline__ void pv16(const float* __restrict__ vp, float e,
                                     float& a0, float& a1, float& a2, float& a3) {
#pragma unroll
  for (int t = 0; t < 16; t += 4) {
    float p0 = rdlane(e, L0 + t + 0);
    float p1 = rdlane(e, L0 + t + 1);
    float p2 = rdlane(e, L0 + t + 2);
    float p3 = rdlane(e, L0 + t + 3);
    a0 += p0 * vp[(t + 0) * 64];
    a1 += p1 * vp[(t + 1) * 64];
    a2 += p2 * vp[(t + 2) * 64];
    a3 += p3 * vp[(t + 3) * 64];
  }
}

// PV over 32 tokens from PACKED bf16 token-pair V (uint = tok t | tok t+1 <<16).
// vp = pair base + lane(dim). Token->chain map (t mod 4) and accumulation
// order identical to the pv16 sequence; only V values are bf16-rounded.
template <int L0>
__device__ __forceinline__ void pv32b(const unsigned* __restrict__ vp, float e,
                                      float& a0, float& a1, float& a2, float& a3) {
#pragma unroll
  for (int t = 0; t < 32; t += 4) {
    unsigned u0 = vp[(t >> 1) * 64];        // tokens t, t+1
    unsigned u1 = vp[(t >> 1) * 64 + 64];   // tokens t+2, t+3
    float p0 = rdlane(e, L0 + t + 0);
    float p1 = rdlane(e, L0 + t + 1);
    float p2 = rdlane(e, L0 + t + 2);
    float p3 = rdlane(e, L0 + t + 3);
    a0 += p0 * __uint_as_float(u0 << 16);
    a1 += p1 * __uint_as_float(u0 & 0xFFFF0000u);
    a2 += p2 * __uint_as_float(u1 << 16);
    a3 += p3 * __uint_as_float(u1 & 0xFFFF0000u);
  }
}

// QK dot against one 32-token K block slice, packed (v_pk_fma_f32).
__device__ __forceinline__ float qk_dot(const float4* __restrict__ qr,
                                        const float4* __restrict__ kp) {
  v2f d01 = {0.f, 0.f}, d23 = {0.f, 0.f};
#pragma unroll 1
  for (int i = 0; i < 16; i += 2) {
    float4 q0 = qr[i],     k0 = kp[i * 32];
    float4 q1 = qr[i + 1], k1 = kp[i * 32 + 32];
    d01 += (v2f){q0.x, q0.y} * (v2f){k0.x, k0.y};
    d23 += (v2f){q0.z, q0.w} * (v2f){k0.z, k0.w};
    d01 += (v2f){q1.x, q1.y} * (v2f){k1.x, k1.y};
    d23 += (v2f){q1.z, q1.w} * (v2f){k1.z, k1.w};
  }
  v2f d = d01 + d23;
  return d.x + d.y;
}

// ---------------- pipelined f32 GEMM core (measured-best 4x4/256t) ----------
__device__ __forceinline__ void gemm_core(
    const float* __restrict__ A, const float* __restrict__ B, float* __restrict__ C,
    int K, int lda, int ldb, int ldc, int row0, int col0)
{
  __shared__ __align__(16) float As[2][16][68];
  __shared__ __align__(16) float Bs[2][16][68];
  const int tid = threadIdx.x;
  const int tx = tid & 15, ty = tid >> 4;
  const int ar = tid >> 2;
  const int ak = (tid & 3) * 4;
  const int bk = tid >> 4;
  const int bc = (tid & 15) * 4;

  const int nk = K >> 4;
  float4 a4 = *reinterpret_cast<const float4*>(&A[(row0 + ar) * lda + ak]);
  float4 b4 = *reinterpret_cast<const float4*>(&B[bk * ldb + col0 + bc]);
  {
    As[0][ak + 0][ar] = a4.x; As[0][ak + 1][ar] = a4.y;
    As[0][ak + 2][ar] = a4.z; As[0][ak + 3][ar] = a4.w;
    *reinterpret_cast<float4*>(&Bs[0][bk][bc]) = b4;
  }

  v2f acc01[4] = {};
  v2f acc23[4] = {};
  for (int t = 0; t < nk; ++t) {
    const int cur = t & 1;
    if (t + 1 < nk) {
      int k0 = (t + 1) * 16;
      a4 = *reinterpret_cast<const float4*>(&A[(row0 + ar) * lda + k0 + ak]);
      b4 = *reinterpret_cast<const float4*>(&B[(k0 + bk) * ldb + col0 + bc]);
    }
    __syncthreads();
#pragma unroll
    for (int kk = 0; kk < 16; ++kk) {
      float4 av = *reinterpret_cast<const float4*>(&As[cur][kk][ty * 4]);
      float4 bv = *reinterpret_cast<const float4*>(&Bs[cur][kk][tx * 4]);
      v2f b01; b01.x = bv.x; b01.y = bv.y;
      v2f b23; b23.x = bv.z; b23.y = bv.w;
      float a[4] = {av.x, av.y, av.z, av.w};
#pragma unroll
      for (int i = 0; i < 4; ++i) {
        v2f as; as.x = a[i]; as.y = a[i];
        acc01[i] += as * b01;
        acc23[i] += as * b23;
      }
    }
    if (t + 1 < nk) {
      const int nxt = cur ^ 1;
      As[nxt][ak + 0][ar] = a4.x; As[nxt][ak + 1][ar] = a4.y;
      As[nxt][ak + 2][ar] = a4.z; As[nxt][ak + 3][ar] = a4.w;
      *reinterpret_cast<float4*>(&Bs[nxt][bk][bc]) = b4;
    }
  }
#pragma unroll
  for (int i = 0; i < 4; ++i) {
    float4 o = make_float4(acc01[i].x, acc01[i].y, acc23[i].x, acc23[i].y);
    *reinterpret_cast<float4*>(&C[(row0 + ty * 4 + i) * ldc + col0 + tx * 4]) = o;
  }
}

__global__ __launch_bounds__(256) void gemm_tile(
    const float* __restrict__ A, const float* __restrict__ B, float* __restrict__ C,
    int M, int N, int K, int lda, int ldb, int ldc)
{
  gemm_core(A, B, C, K, lda, ldb, ldc, blockIdx.y * 64, blockIdx.x * 64);
}

// Fused h-projections: hc (x<4), kb (x==4), vb (x==5). One dispatch, 192 blocks.
__global__ __launch_bounds__(256) void gemm_qckv(
    const float* __restrict__ h, const float* __restrict__ w_qc,
    const float* __restrict__ w_k, const float* __restrict__ w_v,
    float* __restrict__ hc, float* __restrict__ kb, float* __restrict__ vb)
{
  const int x = blockIdx.x;
  if (x < 4) {
    gemm_core(h, w_qc, hc, 1024, 1024, 256, 256, blockIdx.y * 64, x * 64);
  } else if (x == 4) {
    gemm_core(h, w_k, kb, 1024, 1024, 64, 64, blockIdx.y * 64, 0);
  } else {
    gemm_core(h, w_v, vb, 1024, 1024, 64, 64, blockIdx.y * 64, 0);
  }
}

// Pack V into bf16 token-pairs: vbp[t2*64+d] = bf16(v[2t2][d]) | bf16(v[2t2+1][d])<<16
__global__ __launch_bounds__(256) void vconv_kernel(
    const float* __restrict__ vb, unsigned* __restrict__ vbp)
{
  int gid = blockIdx.x * 256 + threadIdx.x;   // 65536
  int t2 = gid >> 6, d = gid & 63;
  unsigned lo = f2bf(vb[(2 * t2) * 64 + d]);
  unsigned hi = f2bf(vb[(2 * t2 + 1) * 64 + d]);
  vbp[gid] = lo | (hi << 16);
}

// Transpose+convert w_out (1024x1024 f32, row-major [k][col]) -> wT bf16 [col][k].
__global__ __launch_bounds__(256) void wtrans_kernel(
    const float* __restrict__ w, unsigned short* __restrict__ wT)
{
  int gid = blockIdx.x * 256 + threadIdx.x;   // 1M threads
  int k = gid >> 10, col = gid & 1023;
  wT[col * 1024 + k] = f2bf(w[k * 1024 + col]);
}

// Transpose+convert w_out_group (2x256x512 f32 [g][f][i]) -> wogT bf16 [g][i][f].
__global__ __launch_bounds__(256) void wogtrans_kernel(
    const float* __restrict__ wog, unsigned short* __restrict__ wogT)
{
  int gid = blockIdx.x * 256 + threadIdx.x;   // 262144 threads
  int g = gid >> 17;
  int rem = gid & 131071;
  int i = rem >> 8;     // col 0..511
  int f = rem & 255;    // k   0..255
  wogT[(g * 512 + i) * 256 + f] = f2bf(wog[g * 131072 + f * 512 + i]);
}

// ---------------- MFMA bf16 group projection: y1b = mxb @ wogT^T ------------
__global__ __launch_bounds__(256) void gemm_group_mfma(
    const unsigned short* __restrict__ mxb, const unsigned short* __restrict__ wogT,
    unsigned short* __restrict__ y1b)
{
  const int lane = threadIdx.x & 63;
  const int wid = threadIdx.x >> 6;
  const int g = blockIdx.x >> 3;               // group 0..1
  const int colbase = (blockIdx.x & 7) * 64;   // within group's 512
  const int rowbase = blockIdx.y * 64 + wid * 16;
  const int rc = lane & 15;
  const int kg = lane >> 4;
  const unsigned short* ap = mxb + (rowbase + rc) * 512 + g * 256 + kg * 8;
  const unsigned short* bp = wogT + (g * 512 + colbase + rc) * 256 + kg * 8;

  f32x4 acc0 = {0.f, 0.f, 0.f, 0.f};
  f32x4 acc1 = {0.f, 0.f, 0.f, 0.f};
  f32x4 acc2 = {0.f, 0.f, 0.f, 0.f};
  f32x4 acc3 = {0.f, 0.f, 0.f, 0.f};
#pragma unroll
  for (int k0 = 0; k0 < 256; k0 += 32) {
    bf16x8 a = *reinterpret_cast<const bf16x8*>(ap + k0);
    bf16x8 b0 = *reinterpret_cast<const bf16x8*>(bp + k0);
    bf16x8 b1 = *reinterpret_cast<const bf16x8*>(bp + 16 * 256 + k0);
    bf16x8 b2 = *reinterpret_cast<const bf16x8*>(bp + 32 * 256 + k0);
    bf16x8 b3 = *reinterpret_cast<const bf16x8*>(bp + 48 * 256 + k0);
    acc0 = __builtin_amdgcn_mfma_f32_16x16x32_bf16(a, b0, acc0, 0, 0, 0);
    acc1 = __builtin_amdgcn_mfma_f32_16x16x32_bf16(a, b1, acc1, 0, 0, 0);
    acc2 = __builtin_amdgcn_mfma_f32_16x16x32_bf16(a, b2, acc2, 0, 0, 0);
    acc3 = __builtin_amdgcn_mfma_f32_16x16x32_bf16(a, b3, acc3, 0, 0, 0);
  }
#pragma unroll
  for (int j = 0; j < 4; ++j) {
    int row = rowbase + kg * 4 + j;
    unsigned short* yp = y1b + row * 1024 + g * 512 + colbase;
    yp[rc]      = f2bf(acc0[j]);
    yp[16 + rc] = f2bf(acc1[j]);
    yp[32 + rc] = f2bf(acc2[j]);
    yp[48 + rc] = f2bf(acc3[j]);
  }
}

// ---------------- MFMA bf16 out-GEMM: out[2048x1024] = y1b @ wT^T (r24) -----
__global__ __launch_bounds__(256) void gemm_out_mfma(
    const unsigned short* __restrict__ y1b, const unsigned short* __restrict__ wT,
    float* __restrict__ out)
{
  const int lane = threadIdx.x & 63;
  const int wid = threadIdx.x >> 6;
  const int rowbase = blockIdx.y * 64 + wid * 16;
  const int colbase = blockIdx.x * 64;
  const int rc = lane & 15;
  const int kg = lane >> 4;
  const unsigned short* ap = y1b + (rowbase + rc) * 1024 + kg * 8;
  const unsigned short* bp = wT + (colbase + rc) * 1024 + kg * 8;

  f32x4 acc0 = {0.f, 0.f, 0.f, 0.f};
  f32x4 acc1 = {0.f, 0.f, 0.f, 0.f};
  f32x4 acc2 = {0.f, 0.f, 0.f, 0.f};
  f32x4 acc3 = {0.f, 0.f, 0.f, 0.f};
#pragma unroll 2
  for (int k0 = 0; k0 < 1024; k0 += 32) {
    bf16x8 a = *reinterpret_cast<const bf16x8*>(ap + k0);
    bf16x8 b0 = *reinterpret_cast<const bf16x8*>(bp + k0);
    bf16x8 b1 = *reinterpret_cast<const bf16x8*>(bp + 16 * 1024 + k0);
    bf16x8 b2 = *reinterpret_cast<const bf16x8*>(bp + 32 * 1024 + k0);
    bf16x8 b3 = *reinterpret_cast<const bf16x8*>(bp + 48 * 1024 + k0);
    acc0 = __builtin_amdgcn_mfma_f32_16x16x32_bf16(a, b0, acc0, 0, 0, 0);
    acc1 = __builtin_amdgcn_mfma_f32_16x16x32_bf16(a, b1, acc1, 0, 0, 0);
    acc2 = __builtin_amdgcn_mfma_f32_16x16x32_bf16(a, b2, acc2, 0, 0, 0);
    acc3 = __builtin_amdgcn_mfma_f32_16x16x32_bf16(a, b3, acc3, 0, 0, 0);
  }
#pragma unroll
  for (int j = 0; j < 4; ++j) {
    int row = rowbase + kg * 4 + j;
    out[row * 1024 + colbase + rc]      = acc0[j];
    out[row * 1024 + colbase + 16 + rc] = acc1[j];
    out[row * 1024 + colbase + 32 + rc] = acc2[j];
    out[row * 1024 + colbase + 48 + rc] = acc3[j];
  }
}

// ---------------- RoPE cos/sin table (double trig once, f32 store) ----------
__global__ __launch_bounds__(256) void rope_table_kernel(float* __restrict__ ct,
                                                         float* __restrict__ st) {
  int tid = blockIdx.x * 256 + threadIdx.x;
  if (tid >= 2048 * 16) return;
  int pos = tid >> 4, i = tid & 15;
  double ang = (double)pos * pow(10000.0, -(double)i / 16.0);
  ct[tid] = (float)cos(ang);
  st[tid] = (float)sin(ang);
}

// ---------------- RoPE (first 32 dims) + RMSNorm (fused q+k) ----------------
__device__ __forceinline__ void rope_body(
    float* __restrict__ x, const float* __restrict__ g, int rows, int posShift,
    float* __restrict__ kS, const float* __restrict__ ct, const float* __restrict__ st,
    int bx)
{
  const int lane = threadIdx.x & 63;
  const int wid = threadIdx.x >> 6;
  const int r = bx * 4 + wid;
  if (r >= rows) return;
  const int pos = r >> posShift;
  float val = x[r * 64 + lane];
  float p = __shfl_xor(val, 16, 64);
  float out = val;
  if (lane < 32) {
    int i = lane & 15;
    float cc = ct[pos * 16 + i], ss = st[pos * 16 + i];
    out = (lane < 16) ? (val * cc - p * ss) : (p * ss + val * cc);
  }
  float ms = wave_sum(out * out) * (1.0f / 64.0f);
  float rn = rsqrtf(ms + 1e-6f);
  float res = out * rn * ldv(g, lane);
  x[r * 64 + lane] = res;
  if (kS) {
    int f4 = (r >> 5) * 512 + (lane >> 2) * 32 + (r & 31);
    kS[f4 * 4 + (lane & 3)] = res;
  }
}

__global__ __launch_bounds__(256) void rope_rms_fused(
    float* __restrict__ qx, float* __restrict__ kx,
    const float* __restrict__ gq, const float* __restrict__ gk,
    float* __restrict__ kS, const float* __restrict__ ct, const float* __restrict__ st)
{
  const int bx = blockIdx.x;
  if (bx < 4096) rope_body(qx, gq, 16384, 3, nullptr, ct, st, bx);
  else           rope_body(kx, gk, 2048, 0, kS, ct, st, bx - 4096);
}

// ---------------- block-mean compression: kcT4 (d4-major) + vc --------------
__global__ void compress_kernel(const float* __restrict__ k, const float* __restrict__ v,
                                float* __restrict__ kcT4, float* __restrict__ vc)
{
  const int n = blockIdx.x;
  const int d = threadIdx.x;
  float sk = 0.f, sv = 0.f;
  for (int j = 0; j < 32; ++j) {
    sk += k[(n * 32 + j) * 64 + d];
    sv += v[(n * 32 + j) * 64 + d];
  }
  kcT4[(d >> 2) * 256 + n * 4 + (d & 3)] = sk * (1.0f / 32.0f);
  vc[n * 64 + d] = sv * (1.0f / 32.0f);
}

// ---------------- attention: 8 waves (= 8 heads) per qpos block --------------
// V consumed as bf16 token-pairs (vbp): PV-only precision change, scores/top-k
// byte-identical. Window K + packed V staged cooperatively in LDS (8-way reuse).
__global__ __launch_bounds__(512) void attn_kernel(
    const float* __restrict__ q, const float* __restrict__ kS, const unsigned* __restrict__ vbp,
    const float* __restrict__ kcT4, const float* __restrict__ vc,
    const float* __restrict__ w_gate, const float* __restrict__ b_gate,
    const float* __restrict__ sink, unsigned short* __restrict__ mixed)
{
  __shared__ __align__(16) float4 stgK[1024];    // 16 KB
  __shared__ __align__(16) unsigned stgVu[2048]; // 8 KB packed V pairs
  __shared__ __align__(16) float shq[8][64];
  __shared__ int shsel[8][16];
  const int tid = threadIdx.x;
  const int lane = tid & 63;
  const int wid = tid >> 6;
  const int qpos = 2047 - blockIdx.x;
  const int h = wid;
  const int r = qpos * 8 + h;
  const float scale = 0.125f;

  float qv = q[r * 64 + lane];
  shq[wid][lane] = qv;

  // ---- gate ----
  float z0 = qv * ldv(w_gate, lane * 3 + 0);
  float z1 = qv * ldv(w_gate, lane * 3 + 1);
  float z2 = qv * ldv(w_gate, lane * 3 + 2);
  z0 = wave_sum(z0) + ldv(b_gate, 0);
  z1 = wave_sum(z1) + ldv(b_gate, 1);
  z2 = wave_sum(z2) + ldv(b_gate, 2);
  float ga0 = 1.f / (1.f + expf(-z0));
  float ga1 = 1.f / (1.f + expf(-z1));
  float ga2 = 1.f / (1.f + expf(-z2));
  float gs = fmaxf(ga0 + ga1 + ga2, 1e-6f);
  float ginv = 1.f / gs;
  ga0 *= ginv; ga1 *= ginv; ga2 *= ginv;

  const float4* qr = reinterpret_cast<const float4*>(&shq[wid][0]);
  const float4* ks4 = reinterpret_cast<const float4*>(kS);
  const float4* kct = reinterpret_cast<const float4*>(kcT4);
  const float snk = ldv(sink, h);
  const int nv = (qpos + 1) >> 5;

  // ======== PHASE 1: per-wave: comp + top-k + selected ========
  float sc;
  {
    float d0 = 0.f, d1 = 0.f;
#pragma unroll 1
    for (int i = 0; i < 16; i += 2) {
      float4 q0 = qr[i],     k0 = kct[i * 64 + lane];
      float4 q1 = qr[i + 1], k1 = kct[(i + 1) * 64 + lane];
      d0 += q0.x * k0.x + q0.z * k0.z;
      d1 += q0.y * k0.y + q0.w * k0.w;
      d0 += q1.x * k1.x + q1.z * k1.z;
      d1 += q1.y * k1.y + q1.w * k1.w;
    }
    sc = (d0 + d1) * scale;
  }

  float comp_out = 0.f;
  if (nv > 0) {
    float scomp = (lane < nv) ? sc : NEGBIG;
    float m = fmaxf(wave_max(scomp), snk);
    float e = (lane < nv) ? expf(sc - m) : 0.f;
    float S = wave_sum(e) + expf(snk - m);
    float pn = e / S;
    const float* vcp = vc + lane;
    float c0 = 0.f, c1 = 0.f, c2 = 0.f, c3 = 0.f;
    pv16<0>(vcp, pn, c0, c1, c2, c3);
    pv16<16>(vcp + 1024, pn, c0, c1, c2, c3);
    pv16<32>(vcp + 2048, pn, c0, c1, c2, c3);
    pv16<48>(vcp + 3072, pn, c0, c1, c2, c3);
    comp_out = (c0 + c1) + (c2 + c3);
  }

  {
    float selv = (lane < nv) ? sc : -FLT_MAX;
#pragma unroll
    for (int it = 0; it < 16; ++it) {
      float bv = selv; int bi = lane;
#pragma unroll
      for (int off = 32; off; off >>= 1) {
        float ov = __shfl_xor(bv, off, 64);
        int oi = __shfl_xor(bi, off, 64);
        if (ov > bv || (ov == bv && oi < bi)) { bv = ov; bi = oi; }
      }
      if (lane == 0) shsel[wid][it] = bi;
      if (lane == bi) selv = -INFINITY;
    }
  }

  float M = NEGBIG, S = 0.f, osel = 0.f;
#pragma unroll 1
  for (int c = 0; c < 8; ++c) {
    int b0 = shsel[wid][2 * c], b1 = shsel[wid][2 * c + 1];
    int base0 = b0 * 32, base1 = b1 * 32;
    if (base0 > qpos && base1 > qpos) continue;
    int myb = (lane < 32) ? b0 : b1;
    int tok = myb * 32 + (lane & 31);
    bool ok = (tok <= qpos);
    const float4* kp = ks4 + myb * 512 + (lane & 31);
    float s = ok ? qk_dot(qr, kp) * scale : NEGBIG;
    float Mn = fmaxf(M, wave_max(s));
    float e = ok ? expf(s - Mn) : 0.f;
    float cs = wave_sum(e);
    float corr = expf(M - Mn);
    S = S * corr + cs;
    const unsigned* v0p = vbp + base0 * 32 + lane;   // (base0>>1)*64
    const unsigned* v1p = vbp + base1 * 32 + lane;
    float a0 = 0.f, a1 = 0.f, a2 = 0.f, a3 = 0.f;
    pv32b<0>(v0p, e, a0, a1, a2, a3);
    pv32b<32>(v1p, e, a0, a1, a2, a3);
    osel = osel * corr + ((a0 + a1) + (a2 + a3));
    M = Mn;
  }
  osel /= S;

  // ======== PHASE 2: window with cooperative LDS staging ========
  float Mw = NEGBIG, Sw = 0.f, osw = 0.f;
  int kstart = qpos - 511; if (kstart < 0) kstart = 0;
  int sbf = kstart >> 5, sbl = qpos >> 5;
#pragma unroll 1
  for (int sb = sbf; sb <= sbl; sb += 2) {
    int sb1 = sb + 1;
    bool v1ok = (sb1 <= sbl);
    int sb1c = v1ok ? sb1 : sb;
    __syncthreads();
#pragma unroll
    for (int j = 0; j < 2; ++j) {
      int g = j * 512 + tid;
      int blk = (g >> 9) ? sb1c : sb;
      stgK[g] = ks4[blk * 512 + (g & 511)];
    }
    // stage packed V: 2048 uints (block sb pairs at [0,1024), sb1c at [1024,2048))
#pragma unroll
    for (int j = 0; j < 4; ++j) {
      int g = j * 512 + tid;
      int blk16 = (g >> 10) ? (sb1c * 16) : (sb * 16);
      stgVu[g] = vbp[blk16 * 64 + (g & 1023)];
    }
    __syncthreads();
    int myoff = (lane < 32) ? 0 : 512;
    int tok = ((lane < 32) ? sb : sb1c) * 32 + (lane & 31);
    bool ok = (tok >= kstart) && (tok <= qpos) && ((lane < 32) || v1ok);
    const float4* kp = stgK + myoff + (lane & 31);
    float s = ok ? qk_dot(qr, kp) * scale : NEGBIG;
    float Mn = fmaxf(Mw, wave_max(s));
    float e = ok ? expf(s - Mn) : 0.f;
    float cs = wave_sum(e);
    float corr = expf(Mw - Mn);
    Sw = Sw * corr + cs;
    const unsigned* v0p = stgVu + lane;          // block sb pairs
    const unsigned* v1p = stgVu + 1024 + lane;   // block sb1c pairs
    float a0 = 0.f, a1 = 0.f, a2 = 0.f, a3 = 0.f;
    pv32b<0>(v0p, e, a0, a1, a2, a3);
    pv32b<32>(v1p, e, a0, a1, a2, a3);
    osw = osw * corr + ((a0 + a1) + (a2 + a3));
    Mw = Mn;
  }
  {
    float Mf = fmaxf(Mw, snk);
    float corr = expf(Mw - Mf);
    float Sf = Sw * corr + expf(snk - Mf);
    osw = osw * corr / Sf;
  }

  mixed[r * 64 + lane] = f2bf(ga0 * comp_out + ga1 * osel + ga2 * osw);
}

// ---------------- launch ----------------
extern "C" void kernel_launch(void* const* d_in, const int* in_sizes, int n_in,
                              void* d_out, int out_size, void* d_ws, size_t ws_size,
                              hipStream_t stream) {
  const float* h      = (const float*)d_in[0];
  const float* w_qc   = (const float*)d_in[1];
  const float* w_qup  = (const float*)d_in[2];
  const float* w_k    = (const float*)d_in[3];
  const float* w_v    = (const float*)d_in[4];
  const float* g_qn   = (const float*)d_in[5];
  const float* g_kn   = (const float*)d_in[6];
  const float* w_gate = (const float*)d_in[7];
  const float* b_gate = (const float*)d_in[8];
  const float* sink   = (const float*)d_in[9];
  const float* wog    = (const float*)d_in[10];
  const float* w_out  = (const float*)d_in[11];
  float* out = (float*)d_out;

  float* ws = (float*)d_ws;
  float* hc  = ws;                    // 2048*256 (dead after qup -> reused as wT)
  float* qb  = hc + 2048 * 256;       // 2048*512
  float* kb  = qb + 2048 * 512;       // 2048*64
  float* vb  = kb + 2048 * 64;        // 2048*64
  float* vc  = vb + 2048 * 64;        // 64*64
  float* mx  = vc + 64 * 64;          // 2048*512 slot (bf16 mixed uses half)
  float* y1  = mx + 2048 * 512;       // 2048*1024 f32 slot (bf16 y1b + wogT)
  float* kS  = y1 + 2048 * 1024;      // 2048*64 block-local K
  float* kct4 = kS + 2048 * 64;       // 16*64*4
  float* ct  = kct4 + 16 * 64 * 4;    // 2048*16 rope cos
  float* st  = ct + 2048 * 16;        // 2048*16 rope sin
  unsigned* vbp = (unsigned*)(st + 2048 * 16);  // 1024*64 packed bf16 V pairs (256KB)

  unsigned short* mxb  = (unsigned short*)mx;             // 2048*512 bf16
  unsigned short* y1b  = (unsigned short*)y1;             // 2048*1024 bf16 (first 4MB)
  unsigned short* wogT = (unsigned short*)(y1 + 1048576); // 2*512*256 bf16 (second half)
  unsigned short* wT   = (unsigned short*)hc;             // 1024*1024 bf16

  dim3 blk(256);
  rope_table_kernel<<<dim3(128), blk, 0, stream>>>(ct, st);
  gemm_qckv<<<dim3(6, 32), blk, 0, stream>>>(h, w_qc, w_k, w_v, hc, kb, vb);
  vconv_kernel<<<dim3(256), blk, 0, stream>>>(vb, vbp);
  gemm_tile<<<dim3(8, 32), blk, 0, stream>>>(hc, w_qup, qb, 2048, 512, 256, 256, 512, 512);
  // hc now dead -> transpose+convert w_out into its slot; wogT into y1 2nd half
  wtrans_kernel<<<dim3(4096), blk, 0, stream>>>(w_out, wT);
  wogtrans_kernel<<<dim3(1024), blk, 0, stream>>>(wog, wogT);
  rope_rms_fused<<<dim3(4608), blk, 0, stream>>>(qb, kb, g_qn, g_kn, kS, ct, st);
  compress_kernel<<<dim3(64), dim3(64), 0, stream>>>(kb, vb, kct4, vc);
  attn_kernel<<<dim3(2048), dim3(512), 0, stream>>>(qb, kS, vbp, kct4, vc, w_gate, b_gate, sink, mxb);
  // group projection via MFMA: y1b = mxb @ wogT^T
  gemm_group_mfma<<<dim3(16, 32), blk, 0, stream>>>(mxb, wogT, y1b);
  // out = y1b @ wT^T via MFMA bf16
  gemm_out_mfma<<<dim3(16, 32), blk, 0, stream>>>(y1b, wT, out);
}